// Round 3
// baseline (1894.700 us; speedup 1.0000x reference)
//
#include <hip/hip_runtime.h>
#include <math.h>

#define B_ 8
#define N_ 4096
#define C_ 768
#define H_ 3072
#define M_ (B_*N_)
#define NSPLIT 16

typedef unsigned short u16;
typedef unsigned int u32;
typedef __attribute__((ext_vector_type(8))) __bf16 bf16x8;
typedef __attribute__((ext_vector_type(4))) float f32x4;
typedef __attribute__((ext_vector_type(4))) unsigned short u16x4;

__device__ __forceinline__ u16 f2bf(float f){
  u32 u = __float_as_uint(f);
  u32 r = (u + 0x7FFFu + ((u >> 16) & 1u)) >> 16;
  return (u16)r;
}
__device__ __forceinline__ float bf2f(u16 h){
  return __uint_as_float(((u32)h) << 16);
}
__device__ __forceinline__ void gload_lds16(const void* g, void* l){
  __builtin_amdgcn_global_load_lds((const __attribute__((address_space(1))) void*)g,
                                   (__attribute__((address_space(3))) void*)l, 16, 0, 0);
}

// ================= 256x256 8-phase GEMM (T2+T3+T4+T5) =================
// C[M,N] = A[M,K](bf16) * BT[N,K](bf16)^T.  512 thr = 8 waves (2Mx4N),
// per-wave 128x64 out = acc[8][4] of 16x16x32 mfma. BK=64 split in 2 k-halves.
// LDS 128KiB: buf{0,1} x { A[256][2kh][32], B[256][2kh][32] }, 16KB half-tiles.
// Half-tile stream h: type h&3: 0=B_k0 1=A_k0 2=B_k1 3=A_k1, K-tile h>>2,
// buf (h>>2)&1. Stage at phase g stages h=g+6 (3 half-tiles in flight after
// each boundary vmcnt(6) at phases 4/8; vmcnt(0) once before last K-tile).
// LDS swizzle: physical 16B-chunk = logical_chunk ^ ((row>>1)&3), applied on
// the pre-swizzled global source (stage) and the ds_read address (read).
// EPI: 0=bf16 out; 1=f32 resid+acc+rowv; 2=bf16 gelu(acc+bias); 3=f32 +=acc+bias

#define MM4(FM, AV) \
  acc[FM][0] = __builtin_amdgcn_mfma_f32_16x16x32_bf16(AV, b0, acc[FM][0],0,0,0); \
  acc[FM][1] = __builtin_amdgcn_mfma_f32_16x16x32_bf16(AV, b1, acc[FM][1],0,0,0); \
  acc[FM][2] = __builtin_amdgcn_mfma_f32_16x16x32_bf16(AV, b2, acc[FM][2],0,0,0); \
  acc[FM][3] = __builtin_amdgcn_mfma_f32_16x16x32_bf16(AV, b3, acc[FM][3],0,0,0);

#define STAGE(H2) do { if ((H2) < Htot){                                     \
  const int kt_ = (H2)>>2, ty_ = (H2)&3;                                     \
  const int kh_ = ty_>>1; const int isA_ = ty_&1;                            \
  const size_t ko_ = (size_t)kt_*64 + (size_t)kh_*32;                        \
  char* ld_ = ldsc + ((kt_&1)<<16) + ((isA_^1)<<15) + (kh_<<14) + tid*16;    \
  const u16* g0_ = (isA_ ? Ap + Ab0 : Bp + Bb0) + ko_;                       \
  const u16* g1_ = (isA_ ? Ap + Ab1 : Bp + Bb1) + ko_;                       \
  gload_lds16(g0_, ld_);                                                     \
  gload_lds16(g1_, ld_ + 8192);                                              \
}} while(0)

#define PHASE(BUFB, KHB, FMQ, LOADB, VMN) do {                               \
  __builtin_amdgcn_sched_barrier(0);                                         \
  const u16* pa_ = ldsu + (((BUFB)+(KHB))>>1) + aoffA;                       \
  bf16x8 a0_ = *(const bf16x8*)(pa_ + ((FMQ)*4+0)*512);                      \
  bf16x8 a1_ = *(const bf16x8*)(pa_ + ((FMQ)*4+1)*512);                      \
  bf16x8 a2_ = *(const bf16x8*)(pa_ + ((FMQ)*4+2)*512);                      \
  bf16x8 a3_ = *(const bf16x8*)(pa_ + ((FMQ)*4+3)*512);                      \
  if (LOADB){                                                                \
    const u16* pb_ = ldsu + (((BUFB)+32768+(KHB))>>1) + boffB;               \
    b0 = *(const bf16x8*)(pb_ + 0*512);                                      \
    b1 = *(const bf16x8*)(pb_ + 1*512);                                      \
    b2 = *(const bf16x8*)(pb_ + 2*512);                                      \
    b3 = *(const bf16x8*)(pb_ + 3*512);                                      \
  }                                                                          \
  STAGE(hh); hh++;                                                           \
  __builtin_amdgcn_sched_barrier(0);                                         \
  __builtin_amdgcn_s_barrier();                                              \
  asm volatile("s_waitcnt lgkmcnt(0)" ::: "memory");                         \
  __builtin_amdgcn_sched_barrier(0);                                         \
  __builtin_amdgcn_s_setprio(1);                                             \
  MM4((FMQ)*4+0, a0_)                                                        \
  MM4((FMQ)*4+1, a1_)                                                        \
  MM4((FMQ)*4+2, a2_)                                                        \
  MM4((FMQ)*4+3, a3_)                                                        \
  __builtin_amdgcn_s_setprio(0);                                             \
  if ((VMN) == 6) { asm volatile("s_waitcnt vmcnt(6)" ::: "memory"); }       \
  else if ((VMN) == 0) { asm volatile("s_waitcnt vmcnt(0)" ::: "memory"); }  \
  __builtin_amdgcn_s_barrier();                                              \
} while(0)

template<int EPI>
__global__ __launch_bounds__(512, 2) void gemm256(
    const u16* __restrict__ Ap, const u16* __restrict__ Bp,
    int K, int N, int NBN,
    void* __restrict__ outp,
    const float* __restrict__ resid,
    const float* __restrict__ rowv,
    const float* __restrict__ bias)
{
  __shared__ __align__(16) char ldsraw[131072];
  char* ldsc = ldsraw;
  const u16* ldsu = (const u16*)ldsraw;

  const int tid = threadIdx.x;
  const int wid = tid >> 6, lane = tid & 63;
  const int wr = wid >> 2, wc = wid & 3;
  const int l15 = lane & 15;

  // block swizzle: XCD chunk (nwg%8==0), bn-fast within chunk
  const int nwg = gridDim.x;
  int wg = blockIdx.x;
  wg = (wg & 7) * (nwg >> 3) + (wg >> 3);
  const int bm = (wg / NBN) * 256;
  const int bn = (wg % NBN) * 256;

  f32x4 acc[8][4];
#pragma unroll
  for (int i=0;i<8;i++)
#pragma unroll
    for (int j=0;j<4;j++) acc[i][j] = (f32x4){0.f,0.f,0.f,0.f};

  // staging per-thread constants: slots s=tid, tid+512; row=s>>2, chunk=s&3,
  // logical chunk = chunk ^ ((row>>1)&3)  (pre-swizzled global source)
  const int r0s = tid >> 2, c0s = (tid & 3) ^ ((tid >> 3) & 3);
  const size_t Ab0 = (size_t)(bm + r0s)*K       + (size_t)c0s*8;
  const size_t Ab1 = (size_t)(bm + 128 + r0s)*K + (size_t)c0s*8;
  const size_t Bb0 = (size_t)(bn + r0s)*K       + (size_t)c0s*8;
  const size_t Bb1 = (size_t)(bn + 128 + r0s)*K + (size_t)c0s*8;

  // fragment read constants (u16 units within a kh region)
  const int physcb = ((lane >> 4) << 4) ^ (((l15 >> 1) & 3) << 4);
  const int aoffA = (wr*128 + l15)*32 + (physcb >> 1);
  const int boffB = (wc*64  + l15)*32 + (physcb >> 1);

  const int T = K >> 6;
  const int Htot = T*4;
  bf16x8 b0, b1, b2, b3;

  // prologue: stage h=0..6, land K-tile 0
  int hh = 0;
  STAGE(0); STAGE(1); STAGE(2); STAGE(3);
  asm volatile("s_waitcnt vmcnt(4)" ::: "memory");
  STAGE(4); STAGE(5); STAGE(6);
  asm volatile("s_waitcnt vmcnt(6)" ::: "memory");
  __builtin_amdgcn_s_barrier();
  hh = 7;

  for (int kt = 0; kt < T; kt += 2){
    const int vm4 = (kt+1 == T-1) ? 0 : 6;
    const int vm8 = (kt+2 >= T) ? -1 : 6;
    PHASE(0,     0,     0, 1, -1);
    PHASE(0,     0,     1, 0, -1);
    PHASE(0,     16384, 0, 1, -1);
    PHASE(0,     16384, 1, 0, vm4);
    PHASE(65536, 0,     0, 1, -1);
    PHASE(65536, 0,     1, 0, -1);
    PHASE(65536, 16384, 0, 1, -1);
    PHASE(65536, 16384, 1, 0, vm8);
  }

  // epilogue: C/D layout col=lane&15, row=(lane>>4)*4+r (verified m89)
  const int col0 = bn + wc*64 + l15;
  const int row0 = bm + wr*128 + ((lane >> 4) << 2);
#pragma unroll
  for (int fm=0; fm<8; fm++){
#pragma unroll
    for (int fn=0; fn<4; fn++){
#pragma unroll
      for (int r2=0; r2<4; r2++){
        const int row = row0 + fm*16 + r2;
        const int cj  = col0 + fn*16;
        const size_t o = (size_t)row*N + cj;
        const float va = acc[fm][fn][r2];
        if constexpr (EPI == 0){
          ((u16*)outp)[o] = f2bf(va);
        } else if constexpr (EPI == 1){
          ((float*)outp)[o] = resid[o] + va + rowv[(row >> 12)*N + cj];
        } else if constexpr (EPI == 2){
          const float z = va + bias[cj];
          ((u16*)outp)[o] = f2bf(0.5f*z*(1.0f + erff(z*0.70710678f)));
        } else {
          float* po = (float*)outp + o;
          *po += va + bias[cj];
        }
      }
    }
  }
}

// ---------------- LayerNorm over last dim (768): wave-per-row, float4 ----------------
__global__ __launch_bounds__(256) void ln_fwd(const float* __restrict__ in,
    const float* __restrict__ gam, const float* __restrict__ bet,
    u16* __restrict__ out)
{
  const int row  = blockIdx.x*4 + (threadIdx.x >> 6);
  const int lane = threadIdx.x & 63;
  const float* p = in + (size_t)row * C_;
  float4 v0 = *reinterpret_cast<const float4*>(p + lane*4);
  float4 v1 = *reinterpret_cast<const float4*>(p + lane*4 + 256);
  float4 v2 = *reinterpret_cast<const float4*>(p + lane*4 + 512);
  float s  = v0.x+v0.y+v0.z+v0.w + v1.x+v1.y+v1.z+v1.w + v2.x+v2.y+v2.z+v2.w;
  float sq = v0.x*v0.x+v0.y*v0.y+v0.z*v0.z+v0.w*v0.w
           + v1.x*v1.x+v1.y*v1.y+v1.z*v1.z+v1.w*v1.w
           + v2.x*v2.x+v2.y*v2.y+v2.z*v2.z+v2.w*v2.w;
#pragma unroll
  for (int o=32;o>0;o>>=1){ s += __shfl_xor(s,o); sq += __shfl_xor(sq,o); }
  const float mu = s * (1.f/C_);
  const float rs = rsqrtf(sq*(1.f/C_) - mu*mu + 1e-5f);
  float4 g0 = *reinterpret_cast<const float4*>(gam + lane*4);
  float4 g1 = *reinterpret_cast<const float4*>(gam + lane*4 + 256);
  float4 g2 = *reinterpret_cast<const float4*>(gam + lane*4 + 512);
  float4 b0 = *reinterpret_cast<const float4*>(bet + lane*4);
  float4 b1 = *reinterpret_cast<const float4*>(bet + lane*4 + 256);
  float4 b2 = *reinterpret_cast<const float4*>(bet + lane*4 + 512);
  u16* op = out + (size_t)row * C_;
  u16x4 o0, o1, o2;
  o0[0]=f2bf((v0.x-mu)*rs*g0.x+b0.x); o0[1]=f2bf((v0.y-mu)*rs*g0.y+b0.y);
  o0[2]=f2bf((v0.z-mu)*rs*g0.z+b0.z); o0[3]=f2bf((v0.w-mu)*rs*g0.w+b0.w);
  o1[0]=f2bf((v1.x-mu)*rs*g1.x+b1.x); o1[1]=f2bf((v1.y-mu)*rs*g1.y+b1.y);
  o1[2]=f2bf((v1.z-mu)*rs*g1.z+b1.z); o1[3]=f2bf((v1.w-mu)*rs*g1.w+b1.w);
  o2[0]=f2bf((v2.x-mu)*rs*g2.x+b2.x); o2[1]=f2bf((v2.y-mu)*rs*g2.y+b2.y);
  o2[2]=f2bf((v2.z-mu)*rs*g2.z+b2.z); o2[3]=f2bf((v2.w-mu)*rs*g2.w+b2.w);
  *reinterpret_cast<u16x4*>(op + lane*4)       = o0;
  *reinterpret_cast<u16x4*>(op + lane*4 + 256) = o1;
  *reinterpret_cast<u16x4*>(op + lane*4 + 512) = o2;
}

// ---------------- f32 -> bf16 convert (vectorized) ----------------
__global__ __launch_bounds__(256) void cvt_bf16(const float* __restrict__ in,
                                                u16* __restrict__ out, int n4)
{
  int i = blockIdx.x*256 + threadIdx.x;
  if (i < n4){
    float4 v = reinterpret_cast<const float4*>(in)[i];
    u16x4 o; o[0]=f2bf(v.x); o[1]=f2bf(v.y); o[2]=f2bf(v.z); o[3]=f2bf(v.w);
    *reinterpret_cast<u16x4*>(out + (size_t)i*4) = o;
  }
}

// ---------------- transpose + convert: in[R,Cc] f32 -> out[Cc,R] bf16 ----------------
__global__ __launch_bounds__(256) void transpose_cvt(const float* __restrict__ in,
    u16* __restrict__ out, int R, int Cc)
{
  __shared__ float tile[32][33];
  const int c0 = blockIdx.x*32, r0 = blockIdx.y*32;
  const int tx = threadIdx.x & 31, ty = threadIdx.x >> 5;
#pragma unroll
  for (int i=0;i<32;i+=8)
    tile[ty+i][tx] = in[(size_t)(r0+ty+i)*Cc + c0+tx];
  __syncthreads();
#pragma unroll
  for (int i=0;i<32;i+=8)
    out[(size_t)(c0+ty+i)*R + r0+tx] = f2bf(tile[tx][ty+i]);
}

// ---------------- mask sum per batch ----------------
__global__ __launch_bounds__(256) void msum_kernel(const float* __restrict__ mask,
                                                   float* __restrict__ msum)
{
  __shared__ float sm[4];
  const int b = blockIdx.x;
  float s = 0.f;
  for (int i=threadIdx.x;i<N_;i+=256) s += mask[(size_t)b*N_+i];
#pragma unroll
  for (int o=32;o>0;o>>=1) s += __shfl_down(s,o);
  if ((threadIdx.x&63)==0) sm[threadIdx.x>>6]=s;
  __syncthreads();
  if (threadIdx.x==0) msum[b] = sm[0]+sm[1]+sm[2]+sm[3];
}

// ---------------- masked pooling partials over n-chunks ----------------
__global__ __launch_bounds__(256) void pool_partial(const u16* __restrict__ q,
    const float* __restrict__ mask, float* __restrict__ pm, float* __restrict__ pa)
{
  const int c = blockIdx.x*256 + threadIdx.x;
  const int b = blockIdx.y, z = blockIdx.z;
  const int n0 = z*(N_/NSPLIT);
  const u16* qp = q + ((size_t)b*N_ + n0)*C_ + c;
  const float* mp = mask + (size_t)b*N_ + n0;
  float am=0.f, aa=0.f;
  for (int n=0;n<N_/NSPLIT;n++){
    float v = bf2f(qp[(size_t)n*C_]);
    float m = mp[n];
    am += v*m; aa += v;
  }
  const size_t o = ((size_t)z*B_ + b)*C_ + c;
  pm[o]=am; pa[o]=aa;
}

__global__ __launch_bounds__(256) void pool_final(const float* __restrict__ pm,
    const float* __restrict__ pa, const float* __restrict__ msum,
    float* __restrict__ fg, float* __restrict__ bg)
{
  const int c = blockIdx.x*256 + threadIdx.x;
  const int b = blockIdx.y;
  float s_m=0.f, s_a=0.f;
  for (int z=0;z<NSPLIT;z++){ size_t o=((size_t)z*B_+b)*C_+c; s_m+=pm[o]; s_a+=pa[o]; }
  const float ms = msum[b];
  fg[b*C_+c] = s_m/(ms + 5e-4f);
  bg[b*C_+c] = (s_a - s_m)/((float)N_ - ms + 5e-4f);
}

__global__ __launch_bounds__(256) void norm_kernel(const float* __restrict__ fg,
    const float* __restrict__ bg, float* __restrict__ fgn, float* __restrict__ bgn)
{
  __shared__ float sm[8];
  const int b = blockIdx.x;
  float f=0.f, g=0.f;
  for (int i=threadIdx.x;i<C_;i+=256){
    float a=fg[b*C_+i]; f+=a*a;
    float c=bg[b*C_+i]; g+=c*c;
  }
#pragma unroll
  for (int o=32;o>0;o>>=1){ f+=__shfl_down(f,o); g+=__shfl_down(g,o); }
  if ((threadIdx.x&63)==0){ sm[threadIdx.x>>6]=f; sm[4+(threadIdx.x>>6)]=g; }
  __syncthreads();
  if (threadIdx.x==0){
    fgn[b]=sqrtf(sm[0]+sm[1]+sm[2]+sm[3]);
    bgn[b]=sqrtf(sm[4]+sm[5]+sm[6]+sm[7]);
  }
}

// ---------------- cosine scores per token ----------------
__global__ __launch_bounds__(256) void score_kernel(const u16* __restrict__ k,
    const float* __restrict__ fg, const float* __restrict__ bg,
    const float* __restrict__ fgn, const float* __restrict__ bgn,
    float* __restrict__ fg_s, float* __restrict__ bg_s)
{
  __shared__ float sm[12];
  const int t = blockIdx.x;
  const int b = t >> 12;
  const u16* kp = k + (size_t)t*C_;
  float df=0.f, db=0.f, kk=0.f;
  for (int i=threadIdx.x;i<C_;i+=256){
    float kv = bf2f(kp[i]);
    df += kv*fg[b*C_+i]; db += kv*bg[b*C_+i]; kk += kv*kv;
  }
#pragma unroll
  for (int o=32;o>0;o>>=1){ df+=__shfl_down(df,o); db+=__shfl_down(db,o); kk+=__shfl_down(kk,o); }
  const int wid = threadIdx.x>>6;
  if ((threadIdx.x&63)==0){ sm[wid]=df; sm[4+wid]=db; sm[8+wid]=kk; }
  __syncthreads();
  if (threadIdx.x==0){
    df=sm[0]+sm[1]+sm[2]+sm[3]; db=sm[4]+sm[5]+sm[6]+sm[7]; kk=sm[8]+sm[9]+sm[10]+sm[11];
    const float kn = sqrtf(kk);
    fg_s[t] = df/(kn*fgn[b]+1e-7f);
    bg_s[t] = db/(kn*bgn[b]+1e-7f);
  }
}

__global__ __launch_bounds__(256) void minmax_kernel(const float* __restrict__ fg_s,
    const float* __restrict__ bg_s, float* __restrict__ mm)
{
  __shared__ float sm[16];
  const int b = blockIdx.x;
  float mnf=1e30f, mxf=-1e30f, mnb=1e30f, mxb=-1e30f;
  for (int i=threadIdx.x;i<N_;i+=256){
    float a = fg_s[(size_t)b*N_+i]; mnf=fminf(mnf,a); mxf=fmaxf(mxf,a);
    float c = bg_s[(size_t)b*N_+i]; mnb=fminf(mnb,c); mxb=fmaxf(mxb,c);
  }
#pragma unroll
  for (int o=32;o>0;o>>=1){
    mnf=fminf(mnf,__shfl_down(mnf,o)); mxf=fmaxf(mxf,__shfl_down(mxf,o));
    mnb=fminf(mnb,__shfl_down(mnb,o)); mxb=fmaxf(mxb,__shfl_down(mxb,o));
  }
  const int wid = threadIdx.x>>6;
  if ((threadIdx.x&63)==0){ sm[wid]=mnf; sm[4+wid]=mxf; sm[8+wid]=mnb; sm[12+wid]=mxb; }
  __syncthreads();
  if (threadIdx.x==0){
    mm[b*4+0]=fminf(fminf(sm[0],sm[1]),fminf(sm[2],sm[3]));
    mm[b*4+1]=fmaxf(fmaxf(sm[4],sm[5]),fmaxf(sm[6],sm[7]));
    mm[b*4+2]=fminf(fminf(sm[8],sm[9]),fminf(sm[10],sm[11]));
    mm[b*4+3]=fmaxf(fmaxf(sm[12],sm[13]),fmaxf(sm[14],sm[15]));
  }
}

// scores -> pseudo_mask out, exp weights, per-block exp partial sums
__global__ __launch_bounds__(256) void scorefin_kernel(const float* __restrict__ fg_s,
    const float* __restrict__ bg_s, const float* __restrict__ mm,
    float* __restrict__ pseudo, float* __restrict__ escr, float* __restrict__ epart)
{
  __shared__ float sm[4];
  const int b = blockIdx.y, z = blockIdx.x;
  const int t = z*256 + threadIdx.x;
  const size_t o = (size_t)b*N_ + t;
  const float mnf=mm[b*4+0], mxf=mm[b*4+1], mnb=mm[b*4+2], mxb=mm[b*4+3];
  const float s = (fg_s[o]-mnf)/(mxf-mnf+1e-7f) - (bg_s[o]-mnb)/(mxb-mnb+1e-7f);
  pseudo[o] = s;
  const float e = expf(s < 0.f ? s - 100.f : s);
  escr[o] = e;
  float ps = e;
#pragma unroll
  for (int off=32;off>0;off>>=1) ps += __shfl_down(ps,off);
  if ((threadIdx.x&63)==0) sm[threadIdx.x>>6]=ps;
  __syncthreads();
  if (threadIdx.x==0) epart[b*16+z] = sm[0]+sm[1]+sm[2]+sm[3];
}

__global__ void denom_kernel(const float* __restrict__ epart, float* __restrict__ denom){
  const int b = threadIdx.x;
  if (b < B_){ float s=0.f; for (int z=0;z<16;z++) s+=epart[b*16+z]; denom[b]=s; }
}

__global__ __launch_bounds__(256) void vsum_partial(const u16* __restrict__ v,
    const float* __restrict__ e, float* __restrict__ pv)
{
  const int c = blockIdx.x*256 + threadIdx.x;
  const int b = blockIdx.y, z = blockIdx.z;
  const int n0 = z*(N_/NSPLIT);
  const u16* vp = v + ((size_t)b*N_ + n0)*C_ + c;
  const float* ep = e + (size_t)b*N_ + n0;
  float acc=0.f;
  for (int n=0;n<N_/NSPLIT;n++) acc += bf2f(vp[(size_t)n*C_])*ep[n];
  pv[((size_t)z*B_+b)*C_+c] = acc;
}

__global__ __launch_bounds__(256) void vsum_final(const float* __restrict__ pv,
    const float* __restrict__ denom, float* __restrict__ qp)
{
  const int c = blockIdx.x*256 + threadIdx.x;
  const int b = blockIdx.y;
  float s=0.f;
  for (int z=0;z<NSPLIT;z++) s += pv[((size_t)z*B_+b)*C_+c];
  qp[b*C_+c] = s/denom[b];
}

__global__ __launch_bounds__(256) void pro_kernel(const float* __restrict__ qp,
    const float* __restrict__ fg, const float* __restrict__ fgn, float* __restrict__ pro)
{
  __shared__ float sm[8];
  __shared__ float simsh;
  const int b = blockIdx.x;
  float d=0.f, qq=0.f;
  for (int i=threadIdx.x;i<C_;i+=256){ float a=qp[b*C_+i]; d+=a*fg[b*C_+i]; qq+=a*a; }
#pragma unroll
  for (int o=32;o>0;o>>=1){ d+=__shfl_down(d,o); qq+=__shfl_down(qq,o); }
  if ((threadIdx.x&63)==0){ sm[threadIdx.x>>6]=d; sm[4+(threadIdx.x>>6)]=qq; }
  __syncthreads();
  if (threadIdx.x==0){
    d=sm[0]+sm[1]+sm[2]+sm[3]; qq=sm[4]+sm[5]+sm[6]+sm[7];
    simsh = (d/(sqrtf(qq)*fgn[b]+1e-7f)+1.f)*0.5f;
  }
  __syncthreads();
  const float sim = simsh;
  for (int i=threadIdx.x;i<C_;i+=256)
    pro[b*C_+i] = sim*fg[b*C_+i] + (1.f-sim)*qp[b*C_+i];
}

// rowv[b][j] = sum_c pro[b][c] * Wp[(C_+c)*C_ + j]   (bottom half of Wpx/Wpy, f32)
__global__ __launch_bounds__(256) void rowvec_kernel(const float* __restrict__ pro,
    const float* __restrict__ Wp, float* __restrict__ row)
{
  const int j = blockIdx.x*256 + threadIdx.x;
  const int b = blockIdx.y;
  const float* w = Wp + (size_t)C_*C_ + j;
  const float* p = pro + b*C_;
  float acc=0.f;
#pragma unroll 4
  for (int c=0;c<C_;c++) acc += p[c]*w[(size_t)c*C_];
  row[b*C_+j] = acc;
}

// ---------------- launcher ----------------
extern "C" void kernel_launch(void* const* d_in, const int* in_sizes, int n_in,
                              void* d_out, int out_size, void* d_ws, size_t ws_size,
                              hipStream_t stream)
{
  const float* x     = (const float*)d_in[0];
  const float* y     = (const float*)d_in[1];
  const float* mask  = (const float*)d_in[2];
  const float* ln1_g = (const float*)d_in[5];
  const float* ln1_b = (const float*)d_in[6];
  const float* Wq    = (const float*)d_in[7];
  const float* Wk    = (const float*)d_in[8];
  const float* Wv    = (const float*)d_in[9];
  const float* Wpx   = (const float*)d_in[10];
  const float* Wpy   = (const float*)d_in[11];
  const float* ln2_g = (const float*)d_in[12];
  const float* ln2_b = (const float*)d_in[13];
  const float* fx1_w = (const float*)d_in[14];
  const float* fx1_b = (const float*)d_in[15];
  const float* fx2_w = (const float*)d_in[16];
  const float* fx2_b = (const float*)d_in[17];
  const float* fy1_w = (const float*)d_in[18];
  const float* fy1_b = (const float*)d_in[19];
  const float* fy2_w = (const float*)d_in[20];
  const float* fy2_b = (const float*)d_in[21];

  float* out    = (float*)d_out;
  float* out_xo = out;
  float* out_yo = out + (size_t)M_*C_;
  float* out_ps = out + 2*(size_t)M_*C_;

  char* ws = (char*)d_ws;
  const size_t ACT = (size_t)M_*C_;        // 25165824 elems
  u16* R0  = (u16*)ws;
  u16* xnb = R0;                           // xn bf16 (later: x bf16)
  u16* ynb = R0 + ACT;                     // yn bf16 (later: y bf16)
  u16* kb  = R0 + 2*ACT;                   // k bf16
  u16* vb  = R0 + 3*ACT;                   // v bf16
  u16* hid = R0;                           // MLP hidden bf16 [M,H] aliases all of R0
  u16* qb  = (u16*)(ws + 4*ACT*2);         // q bf16 (later: ln2 out bf16)
  u16* wp  = (u16*)(ws + 5*ACT*2);         // bf16 weights
  u16* WqT  = wp;
  u16* WkT  = wp + 1*589824;
  u16* WvT  = wp + 2*589824;
  u16* WpxT = wp + 3*589824;
  u16* WpyT = wp + 4*589824;
  u16* fx1T = wp + 5*589824;
  u16* fx2T = fx1T + 2359296;
  u16* fy1T = fx2T + 2359296;
  u16* fy2T = fy1T + 2359296;
  float* st   = (float*)(ws + 5*ACT*2 + 24772608);
  float* msum = st;             // 8
  float* fgn  = st + 8;         // 8
  float* bgn  = st + 16;        // 8
  float* denom= st + 24;        // 8
  float* mm   = st + 32;        // 32
  float* fg   = st + 64;        // 6144
  float* bg   = st + 6208;      // 6144
  float* qp   = st + 12352;     // 6144
  float* pro  = st + 18496;     // 6144
  float* rowx = st + 24640;     // 6144
  float* rowy = st + 30784;     // 6144
  float* epart= st + 36928;     // 128
  float* fg_s = st + 37056;     // 32768
  float* bg_s = st + 69824;     // 32768
  float* escr = st + 102592;    // 32768
  float* pm   = st + 135360;    // 98304
  float* pa   = st + 233664;    // 98304
  float* pv   = st + 331968;    // 98304

  dim3 tb(256);
  dim3 tg(512);

  // --- weights -> bf16, transposed to [N,K] ---
  transpose_cvt<<<dim3(24,24),tb,0,stream>>>(Wq,  WqT,  C_, C_);
  transpose_cvt<<<dim3(24,24),tb,0,stream>>>(Wk,  WkT,  C_, C_);
  transpose_cvt<<<dim3(24,24),tb,0,stream>>>(Wv,  WvT,  C_, C_);
  transpose_cvt<<<dim3(24,24),tb,0,stream>>>(Wpx, WpxT, C_, C_);
  transpose_cvt<<<dim3(24,24),tb,0,stream>>>(Wpy, WpyT, C_, C_);
  transpose_cvt<<<dim3(96,24),tb,0,stream>>>(fx1_w, fx1T, C_, H_);
  transpose_cvt<<<dim3(24,96),tb,0,stream>>>(fx2_w, fx2T, H_, C_);
  transpose_cvt<<<dim3(96,24),tb,0,stream>>>(fy1_w, fy1T, C_, H_);
  transpose_cvt<<<dim3(24,96),tb,0,stream>>>(fy2_w, fy2T, H_, C_);

  // --- LN1 ---
  ln_fwd<<<M_/4,tb,0,stream>>>(x, ln1_g, ln1_b, xnb);
  ln_fwd<<<M_/4,tb,0,stream>>>(y, ln1_g, ln1_b, ynb);

  // --- q,k,v GEMMs (M/256 x N/256 blocks) ---
  gemm256<0><<<dim3(128*3),tg,0,stream>>>(ynb, WqT, C_, C_, 3, qb, nullptr,nullptr,nullptr);
  gemm256<0><<<dim3(128*3),tg,0,stream>>>(xnb, WkT, C_, C_, 3, kb, nullptr,nullptr,nullptr);
  gemm256<0><<<dim3(128*3),tg,0,stream>>>(xnb, WvT, C_, C_, 3, vb, nullptr,nullptr,nullptr);

  // --- pooled prototypes + scores ---
  msum_kernel<<<B_,tb,0,stream>>>(mask, msum);
  pool_partial<<<dim3(3,B_,NSPLIT),tb,0,stream>>>(qb, mask, pm, pa);
  pool_final<<<dim3(3,B_),tb,0,stream>>>(pm, pa, msum, fg, bg);
  norm_kernel<<<B_,tb,0,stream>>>(fg, bg, fgn, bgn);
  score_kernel<<<M_,tb,0,stream>>>(kb, fg, bg, fgn, bgn, fg_s, bg_s);
  minmax_kernel<<<B_,tb,0,stream>>>(fg_s, bg_s, mm);
  scorefin_kernel<<<dim3(16,B_),tb,0,stream>>>(fg_s, bg_s, mm, out_ps, escr, epart);
  denom_kernel<<<1,64,0,stream>>>(epart, denom);
  vsum_partial<<<dim3(3,B_,NSPLIT),tb,0,stream>>>(vb, escr, pv);
  vsum_final<<<dim3(3,B_),tb,0,stream>>>(pv, denom, qp);
  pro_kernel<<<B_,tb,0,stream>>>(qp, fg, fgn, pro);
  rowvec_kernel<<<dim3(3,B_),tb,0,stream>>>(pro, Wpx, rowx);
  rowvec_kernel<<<dim3(3,B_),tb,0,stream>>>(pro, Wpy, rowy);

  // --- x,y -> bf16 (reuse xn/yn slots; xn/yn dead after qkv GEMMs) ---
  cvt_bf16<<<(ACT/4+255)/256,tb,0,stream>>>(x, xnb, (int)(ACT/4));
  cvt_bf16<<<(ACT/4+255)/256,tb,0,stream>>>(y, ynb, (int)(ACT/4));

  // --- projection GEMMs: out = resid + act@WpA + pro@WpB ---
  gemm256<1><<<dim3(128*3),tg,0,stream>>>(xnb, WpxT, C_, C_, 3, out_xo, x, rowx, nullptr);
  gemm256<1><<<dim3(128*3),tg,0,stream>>>(ynb, WpyT, C_, C_, 3, out_yo, y, rowy, nullptr);

  // --- x MLP ---
  ln_fwd<<<M_/4,tb,0,stream>>>(out_xo, ln2_g, ln2_b, qb);
  gemm256<2><<<dim3(128*12),tg,0,stream>>>(qb, fx1T, C_, H_, 12, hid, nullptr,nullptr, fx1_b);
  gemm256<3><<<dim3(128*3),tg,0,stream>>>(hid, fx2T, H_, C_, 3, out_xo, nullptr,nullptr, fx2_b);

  // --- y MLP ---
  ln_fwd<<<M_/4,tb,0,stream>>>(out_yo, ln2_g, ln2_b, qb);
  gemm256<2><<<dim3(128*12),tg,0,stream>>>(qb, fy1T, C_, H_, 12, hid, nullptr,nullptr, fy1_b);
  gemm256<3><<<dim3(128*3),tg,0,stream>>>(hid, fy2T, H_, C_, 3, out_yo, nullptr,nullptr, fy2_b);
}

// Round 4
// 1865.604 us; speedup vs baseline: 1.0156x; 1.0156x over previous
//
#include <hip/hip_runtime.h>
#include <math.h>

#define B_ 8
#define N_ 4096
#define C_ 768
#define H_ 3072
#define M_ (B_*N_)
#define NSPLIT 16

typedef unsigned short u16;
typedef unsigned int u32;
typedef __attribute__((ext_vector_type(8))) __bf16 bf16x8;
typedef __attribute__((ext_vector_type(4))) float f32x4;
typedef __attribute__((ext_vector_type(4))) unsigned short u16x4;

__device__ __forceinline__ u16 f2bf(float f){
  u32 u = __float_as_uint(f);
  u32 r = (u + 0x7FFFu + ((u >> 16) & 1u)) >> 16;
  return (u16)r;
}
__device__ __forceinline__ float bf2f(u16 h){
  return __uint_as_float(((u32)h) << 16);
}
__device__ __forceinline__ void gload_lds16(const void* g, void* l){
  __builtin_amdgcn_global_load_lds((const __attribute__((address_space(1))) void*)g,
                                   (__attribute__((address_space(3))) void*)l, 16, 0, 0);
}

// ---------------- GEMM: C[M,N] = A[M,K](bf16) * BT[N,K](bf16)^T ----------------
// 128x128 tile, 4 waves (2x2), 4x4 mfma_f32_16x16x32_bf16 per wave.
// 2-phase pipeline: double-buffered LDS, STAGE(next) issued before compute(cur),
// single __syncthreads per K-iter. (R2 structure: 552 TF, 2.7 blocks/CU.)
// EPI: 0 = write bf16
//      1 = out_f32 = resid + acc + rowv[batch(row)]   (xo/yo projection)
//      2 = out_bf16 = gelu(acc + bias)                (MLP hidden)
//      3 = out_f32 += acc + bias                      (MLP second GEMM)
template<int EPI>
__global__ __launch_bounds__(256) void gemm_bf16(
    const u16* __restrict__ A, const u16* __restrict__ BT,
    int K, int N, int NBN,
    void* __restrict__ outp,
    const float* __restrict__ resid,
    const float* __restrict__ rowv,
    const float* __restrict__ bias)
{
  __shared__ u16 lds[2][8192];   // per buf: A[128][32] then B[128][32]
  const int tid = threadIdx.x;
  const int wid = tid >> 6, lane = tid & 63;

  // --- block swizzle: XCD chunk + GM=8 row grouping ---
  const int nwg = gridDim.x;
  int wg = blockIdx.x;
  wg = (wg & 7) * (nwg >> 3) + (wg >> 3);      // bijective (nwg%8==0)
  const int GMN = 8 * NBN;
  const int g = wg / GMN, r = wg % GMN;
  const int bm = (g*8 + (r & 7)) * 128;
  const int bn = (r >> 3) * 128;

  const int wr = wid >> 1, wc = wid & 1;

  f32x4 acc[4][4];
#pragma unroll
  for (int i=0;i<4;i++)
#pragma unroll
    for (int j=0;j<4;j++) acc[i][j] = (f32x4){0.f,0.f,0.f,0.f};

  const int idx0 = tid, idx1 = tid + 256;
  const u16* agp0 = A  + (size_t)(bm + (idx0>>2))*K + (idx0&3)*8;
  const u16* agp1 = A  + (size_t)(bm + (idx1>>2))*K + (idx1&3)*8;
  const u16* bgp0 = BT + (size_t)(bn + (idx0>>2))*K + (idx0&3)*8;
  const u16* bgp1 = BT + (size_t)(bn + (idx1>>2))*K + (idx1&3)*8;

  auto STAGE = [&](int c){
    u16* base = lds[c];
    gload_lds16(agp0, base + wid*512);
    gload_lds16(agp1, base + 2048 + wid*512);
    gload_lds16(bgp0, base + 4096 + wid*512);
    gload_lds16(bgp1, base + 6144 + wid*512);
    agp0 += 32; agp1 += 32; bgp0 += 32; bgp1 += 32;
  };

  const int aoff = (wr*64 + (lane&15))*32 + (lane>>4)*8;
  const int boff = 4096 + (wc*64 + (lane&15))*32 + (lane>>4)*8;

  const int nk = K >> 5;
  STAGE(0);
  __syncthreads();
  int cur = 0;
  for (int kk=0; kk<nk; kk++){
    if (kk+1 < nk) STAGE(cur^1);
    bf16x8 av[4], bv[4];
    const u16* pa = &lds[cur][aoff];
    const u16* pb = &lds[cur][boff];
#pragma unroll
    for (int i=0;i<4;i++){
      av[i] = *reinterpret_cast<const bf16x8*>(pa + i*512);
      bv[i] = *reinterpret_cast<const bf16x8*>(pb + i*512);
    }
#pragma unroll
    for (int i=0;i<4;i++)
#pragma unroll
      for (int j=0;j<4;j++)
        acc[i][j] = __builtin_amdgcn_mfma_f32_16x16x32_bf16(av[i], bv[j], acc[i][j], 0, 0, 0);
    __syncthreads();
    cur ^= 1;
  }

  // C/D layout (verified m89): col = lane&15, row = (lane>>4)*4 + r
  const int col0 = bn + wc*64 + (lane & 15);
  const int row0 = bm + wr*64 + ((lane >> 4) << 2);
#pragma unroll
  for (int i=0;i<4;i++){
#pragma unroll
    for (int j=0;j<4;j++){
#pragma unroll
      for (int r2=0;r2<4;r2++){
        const int row = row0 + i*16 + r2;
        const int cj  = col0 + j*16;
        const size_t o = (size_t)row*N + cj;
        const float va = acc[i][j][r2];
        if constexpr (EPI == 0){
          ((u16*)outp)[o] = f2bf(va);
        } else if constexpr (EPI == 1){
          ((float*)outp)[o] = resid[o] + va + rowv[(row >> 12)*N + cj];
        } else if constexpr (EPI == 2){
          const float z = va + bias[cj];
          ((u16*)outp)[o] = f2bf(0.5f*z*(1.0f + erff(z*0.70710678f)));
        } else {
          float* po = (float*)outp + o;
          *po += va + bias[cj];
        }
      }
    }
  }
}

// ---------------- LayerNorm over last dim (768): wave-per-row, float4 ----------------
__global__ __launch_bounds__(256) void ln_fwd(const float* __restrict__ in,
    const float* __restrict__ gam, const float* __restrict__ bet,
    u16* __restrict__ out)
{
  const int row  = blockIdx.x*4 + (threadIdx.x >> 6);
  const int lane = threadIdx.x & 63;
  const float* p = in + (size_t)row * C_;
  float4 v0 = *reinterpret_cast<const float4*>(p + lane*4);
  float4 v1 = *reinterpret_cast<const float4*>(p + lane*4 + 256);
  float4 v2 = *reinterpret_cast<const float4*>(p + lane*4 + 512);
  float s  = v0.x+v0.y+v0.z+v0.w + v1.x+v1.y+v1.z+v1.w + v2.x+v2.y+v2.z+v2.w;
  float sq = v0.x*v0.x+v0.y*v0.y+v0.z*v0.z+v0.w*v0.w
           + v1.x*v1.x+v1.y*v1.y+v1.z*v1.z+v1.w*v1.w
           + v2.x*v2.x+v2.y*v2.y+v2.z*v2.z+v2.w*v2.w;
#pragma unroll
  for (int o=32;o>0;o>>=1){ s += __shfl_xor(s,o); sq += __shfl_xor(sq,o); }
  const float mu = s * (1.f/C_);
  const float rs = rsqrtf(sq*(1.f/C_) - mu*mu + 1e-5f);
  float4 g0 = *reinterpret_cast<const float4*>(gam + lane*4);
  float4 g1 = *reinterpret_cast<const float4*>(gam + lane*4 + 256);
  float4 g2 = *reinterpret_cast<const float4*>(gam + lane*4 + 512);
  float4 b0 = *reinterpret_cast<const float4*>(bet + lane*4);
  float4 b1 = *reinterpret_cast<const float4*>(bet + lane*4 + 256);
  float4 b2 = *reinterpret_cast<const float4*>(bet + lane*4 + 512);
  u16* op = out + (size_t)row * C_;
  u16x4 o0, o1, o2;
  o0[0]=f2bf((v0.x-mu)*rs*g0.x+b0.x); o0[1]=f2bf((v0.y-mu)*rs*g0.y+b0.y);
  o0[2]=f2bf((v0.z-mu)*rs*g0.z+b0.z); o0[3]=f2bf((v0.w-mu)*rs*g0.w+b0.w);
  o1[0]=f2bf((v1.x-mu)*rs*g1.x+b1.x); o1[1]=f2bf((v1.y-mu)*rs*g1.y+b1.y);
  o1[2]=f2bf((v1.z-mu)*rs*g1.z+b1.z); o1[3]=f2bf((v1.w-mu)*rs*g1.w+b1.w);
  o2[0]=f2bf((v2.x-mu)*rs*g2.x+b2.x); o2[1]=f2bf((v2.y-mu)*rs*g2.y+b2.y);
  o2[2]=f2bf((v2.z-mu)*rs*g2.z+b2.z); o2[3]=f2bf((v2.w-mu)*rs*g2.w+b2.w);
  *reinterpret_cast<u16x4*>(op + lane*4)       = o0;
  *reinterpret_cast<u16x4*>(op + lane*4 + 256) = o1;
  *reinterpret_cast<u16x4*>(op + lane*4 + 512) = o2;
}

// ---------------- f32 -> bf16 convert (vectorized) ----------------
__global__ __launch_bounds__(256) void cvt_bf16(const float* __restrict__ in,
                                                u16* __restrict__ out, int n4)
{
  int i = blockIdx.x*256 + threadIdx.x;
  if (i < n4){
    float4 v = reinterpret_cast<const float4*>(in)[i];
    u16x4 o; o[0]=f2bf(v.x); o[1]=f2bf(v.y); o[2]=f2bf(v.z); o[3]=f2bf(v.w);
    *reinterpret_cast<u16x4*>(out + (size_t)i*4) = o;
  }
}

// ---------------- transpose + convert: in[R,Cc] f32 -> out[Cc,R] bf16 ----------------
__global__ __launch_bounds__(256) void transpose_cvt(const float* __restrict__ in,
    u16* __restrict__ out, int R, int Cc)
{
  __shared__ float tile[32][33];
  const int c0 = blockIdx.x*32, r0 = blockIdx.y*32;
  const int tx = threadIdx.x & 31, ty = threadIdx.x >> 5;
#pragma unroll
  for (int i=0;i<32;i+=8)
    tile[ty+i][tx] = in[(size_t)(r0+ty+i)*Cc + c0+tx];
  __syncthreads();
#pragma unroll
  for (int i=0;i<32;i+=8)
    out[(size_t)(c0+ty+i)*R + r0+tx] = f2bf(tile[tx][ty+i]);
}

// ---------------- mask sum per batch ----------------
__global__ __launch_bounds__(256) void msum_kernel(const float* __restrict__ mask,
                                                   float* __restrict__ msum)
{
  __shared__ float sm[4];
  const int b = blockIdx.x;
  float s = 0.f;
  for (int i=threadIdx.x;i<N_;i+=256) s += mask[(size_t)b*N_+i];
#pragma unroll
  for (int o=32;o>0;o>>=1) s += __shfl_down(s,o);
  if ((threadIdx.x&63)==0) sm[threadIdx.x>>6]=s;
  __syncthreads();
  if (threadIdx.x==0) msum[b] = sm[0]+sm[1]+sm[2]+sm[3];
}

// ---------------- masked pooling partials of yn (bf16) over n-chunks ----------------
__global__ __launch_bounds__(256) void pool_partial(const u16* __restrict__ q,
    const float* __restrict__ mask, float* __restrict__ pm, float* __restrict__ pa)
{
  const int c = blockIdx.x*256 + threadIdx.x;
  const int b = blockIdx.y, z = blockIdx.z;
  const int n0 = z*(N_/NSPLIT);
  const u16* qp = q + ((size_t)b*N_ + n0)*C_ + c;
  const float* mp = mask + (size_t)b*N_ + n0;
  float am=0.f, aa=0.f;
  for (int n=0;n<N_/NSPLIT;n++){
    float v = bf2f(qp[(size_t)n*C_]);
    float m = mp[n];
    am += v*m; aa += v;
  }
  const size_t o = ((size_t)z*B_ + b)*C_ + c;
  pm[o]=am; pa[o]=aa;
}

// ym_s = pooled(mask*yn)/(msum+eps); yd_s = pooled((1-m)*yn)/(N-msum+eps)
__global__ __launch_bounds__(256) void pool_final(const float* __restrict__ pm,
    const float* __restrict__ pa, const float* __restrict__ msum,
    float* __restrict__ fgin, float* __restrict__ bgin)
{
  const int c = blockIdx.x*256 + threadIdx.x;
  const int b = blockIdx.y;
  float s_m=0.f, s_a=0.f;
  for (int z=0;z<NSPLIT;z++){ size_t o=((size_t)z*B_+b)*C_+c; s_m+=pm[o]; s_a+=pa[o]; }
  const float ms = msum[b];
  fgin[b*C_+c] = s_m/(ms + 5e-4f);
  bgin[b*C_+c] = (s_a - s_m)/((float)N_ - ms + 5e-4f);
}

// ---------------- tiny vec-mat: out[b,j] = sum_c in[b,c]*W[(c+rowoff)*C_+j] ----------------
__global__ __launch_bounds__(256) void vecmat(const float* __restrict__ in,
    const float* __restrict__ W, int rowoff, float* __restrict__ outv)
{
  const int j = blockIdx.x*256 + threadIdx.x;
  const int b = blockIdx.y;
  const float* w = W + (size_t)rowoff*C_ + j;
  const float* p = in + b*C_;
  float acc=0.f;
#pragma unroll 4
  for (int c=0;c<C_;c++) acc += p[c]*w[(size_t)c*C_];
  outv[b*C_+j] = acc;
}

// dual-input vec-mat sharing W reads: fg = in1@W, bg = in2@W
__global__ __launch_bounds__(256) void vecmat2(const float* __restrict__ in1,
    const float* __restrict__ in2, const float* __restrict__ W,
    float* __restrict__ o1, float* __restrict__ o2)
{
  const int j = blockIdx.x*256 + threadIdx.x;
  const int b = blockIdx.y;
  const float* w = W + j;
  const float* p1 = in1 + b*C_;
  const float* p2 = in2 + b*C_;
  float a1=0.f, a2=0.f;
#pragma unroll 4
  for (int c=0;c<C_;c++){ float wv = w[(size_t)c*C_]; a1 += p1[c]*wv; a2 += p2[c]*wv; }
  o1[b*C_+j]=a1; o2[b*C_+j]=a2;
}

__global__ __launch_bounds__(256) void norm_kernel(const float* __restrict__ fg,
    const float* __restrict__ bg, float* __restrict__ fgn, float* __restrict__ bgn)
{
  __shared__ float sm[8];
  const int b = blockIdx.x;
  float f=0.f, g=0.f;
  for (int i=threadIdx.x;i<C_;i+=256){
    float a=fg[b*C_+i]; f+=a*a;
    float c=bg[b*C_+i]; g+=c*c;
  }
#pragma unroll
  for (int o=32;o>0;o>>=1){ f+=__shfl_down(f,o); g+=__shfl_down(g,o); }
  if ((threadIdx.x&63)==0){ sm[threadIdx.x>>6]=f; sm[4+(threadIdx.x>>6)]=g; }
  __syncthreads();
  if (threadIdx.x==0){
    fgn[b]=sqrtf(sm[0]+sm[1]+sm[2]+sm[3]);
    bgn[b]=sqrtf(sm[4]+sm[5]+sm[6]+sm[7]);
  }
}

// ---------------- cosine scores per token ----------------
__global__ __launch_bounds__(256) void score_kernel(const u16* __restrict__ k,
    const float* __restrict__ fg, const float* __restrict__ bg,
    const float* __restrict__ fgn, const float* __restrict__ bgn,
    float* __restrict__ fg_s, float* __restrict__ bg_s)
{
  __shared__ float sm[12];
  const int t = blockIdx.x;
  const int b = t >> 12;
  const u16* kp = k + (size_t)t*C_;
  float df=0.f, db=0.f, kk=0.f;
  for (int i=threadIdx.x;i<C_;i+=256){
    float kv = bf2f(kp[i]);
    df += kv*fg[b*C_+i]; db += kv*bg[b*C_+i]; kk += kv*kv;
  }
#pragma unroll
  for (int o=32;o>0;o>>=1){ df+=__shfl_down(df,o); db+=__shfl_down(db,o); kk+=__shfl_down(kk,o); }
  const int wid = threadIdx.x>>6;
  if ((threadIdx.x&63)==0){ sm[wid]=df; sm[4+wid]=db; sm[8+wid]=kk; }
  __syncthreads();
  if (threadIdx.x==0){
    df=sm[0]+sm[1]+sm[2]+sm[3]; db=sm[4]+sm[5]+sm[6]+sm[7]; kk=sm[8]+sm[9]+sm[10]+sm[11];
    const float kn = sqrtf(kk);
    fg_s[t] = df/(kn*fgn[b]+1e-7f);
    bg_s[t] = db/(kn*bgn[b]+1e-7f);
  }
}

__global__ __launch_bounds__(256) void minmax_kernel(const float* __restrict__ fg_s,
    const float* __restrict__ bg_s, float* __restrict__ mm)
{
  __shared__ float sm[16];
  const int b = blockIdx.x;
  float mnf=1e30f, mxf=-1e30f, mnb=1e30f, mxb=-1e30f;
  for (int i=threadIdx.x;i<N_;i+=256){
    float a = fg_s[(size_t)b*N_+i]; mnf=fminf(mnf,a); mxf=fmaxf(mxf,a);
    float c = bg_s[(size_t)b*N_+i]; mnb=fminf(mnb,c); mxb=fmaxf(mxb,c);
  }
#pragma unroll
  for (int o=32;o>0;o>>=1){
    mnf=fminf(mnf,__shfl_down(mnf,o)); mxf=fmaxf(mxf,__shfl_down(mxf,o));
    mnb=fminf(mnb,__shfl_down(mnb,o)); mxb=fmaxf(mxb,__shfl_down(mxb,o));
  }
  const int wid = threadIdx.x>>6;
  if ((threadIdx.x&63)==0){ sm[wid]=mnf; sm[4+wid]=mxf; sm[8+wid]=mnb; sm[12+wid]=mxb; }
  __syncthreads();
  if (threadIdx.x==0){
    mm[b*4+0]=fminf(fminf(sm[0],sm[1]),fminf(sm[2],sm[3]));
    mm[b*4+1]=fmaxf(fmaxf(sm[4],sm[5]),fmaxf(sm[6],sm[7]));
    mm[b*4+2]=fminf(fminf(sm[8],sm[9]),fminf(sm[10],sm[11]));
    mm[b*4+3]=fmaxf(fmaxf(sm[12],sm[13]),fmaxf(sm[14],sm[15]));
  }
}

// scores -> pseudo_mask out, exp weights, per-block exp partial sums
__global__ __launch_bounds__(256) void scorefin_kernel(const float* __restrict__ fg_s,
    const float* __restrict__ bg_s, const float* __restrict__ mm,
    float* __restrict__ pseudo, float* __restrict__ escr, float* __restrict__ epart)
{
  __shared__ float sm[4];
  const int b = blockIdx.y, z = blockIdx.x;
  const int t = z*256 + threadIdx.x;
  const size_t o = (size_t)b*N_ + t;
  const float mnf=mm[b*4+0], mxf=mm[b*4+1], mnb=mm[b*4+2], mxb=mm[b*4+3];
  const float s = (fg_s[o]-mnf)/(mxf-mnf+1e-7f) - (bg_s[o]-mnb)/(mxb-mnb+1e-7f);
  pseudo[o] = s;
  const float e = expf(s < 0.f ? s - 100.f : s);
  escr[o] = e;
  float ps = e;
#pragma unroll
  for (int off=32;off>0;off>>=1) ps += __shfl_down(ps,off);
  if ((threadIdx.x&63)==0) sm[threadIdx.x>>6]=ps;
  __syncthreads();
  if (threadIdx.x==0) epart[b*16+z] = sm[0]+sm[1]+sm[2]+sm[3];
}

__global__ void denom_kernel(const float* __restrict__ epart, float* __restrict__ denom){
  const int b = threadIdx.x;
  if (b < B_){ float s=0.f; for (int z=0;z<16;z++) s+=epart[b*16+z]; denom[b]=s; }
}

// attn-pool of xn: pv partials of sum_n escr*xn
__global__ __launch_bounds__(256) void vpool_partial(const u16* __restrict__ xn,
    const float* __restrict__ e, float* __restrict__ pv)
{
  const int c = blockIdx.x*256 + threadIdx.x;
  const int b = blockIdx.y, z = blockIdx.z;
  const int n0 = z*(N_/NSPLIT);
  const u16* vp = xn + ((size_t)b*N_ + n0)*C_ + c;
  const float* ep = e + (size_t)b*N_ + n0;
  float acc=0.f;
  for (int n=0;n<N_/NSPLIT;n++) acc += bf2f(vp[(size_t)n*C_])*ep[n];
  pv[((size_t)z*B_+b)*C_+c] = acc;
}

__global__ __launch_bounds__(256) void vpool_final(const float* __restrict__ pv,
    const float* __restrict__ denom, float* __restrict__ vpin)
{
  const int c = blockIdx.x*256 + threadIdx.x;
  const int b = blockIdx.y;
  float s=0.f;
  for (int z=0;z<NSPLIT;z++) s += pv[((size_t)z*B_+b)*C_+c];
  vpin[b*C_+c] = s/denom[b];
}

__global__ __launch_bounds__(256) void pro_kernel(const float* __restrict__ qp,
    const float* __restrict__ fg, const float* __restrict__ fgn, float* __restrict__ pro)
{
  __shared__ float sm[8];
  __shared__ float simsh;
  const int b = blockIdx.x;
  float d=0.f, qq=0.f;
  for (int i=threadIdx.x;i<C_;i+=256){ float a=qp[b*C_+i]; d+=a*fg[b*C_+i]; qq+=a*a; }
#pragma unroll
  for (int o=32;o>0;o>>=1){ d+=__shfl_down(d,o); qq+=__shfl_down(qq,o); }
  if ((threadIdx.x&63)==0){ sm[threadIdx.x>>6]=d; sm[4+(threadIdx.x>>6)]=qq; }
  __syncthreads();
  if (threadIdx.x==0){
    d=sm[0]+sm[1]+sm[2]+sm[3]; qq=sm[4]+sm[5]+sm[6]+sm[7];
    simsh = (d/(sqrtf(qq)*fgn[b]+1e-7f)+1.f)*0.5f;
  }
  __syncthreads();
  const float sim = simsh;
  for (int i=threadIdx.x;i<C_;i+=256)
    pro[b*C_+i] = sim*fg[b*C_+i] + (1.f-sim)*qp[b*C_+i];
}

// ---------------- launcher ----------------
extern "C" void kernel_launch(void* const* d_in, const int* in_sizes, int n_in,
                              void* d_out, int out_size, void* d_ws, size_t ws_size,
                              hipStream_t stream)
{
  const float* x     = (const float*)d_in[0];
  const float* y     = (const float*)d_in[1];
  const float* mask  = (const float*)d_in[2];
  const float* ln1_g = (const float*)d_in[5];
  const float* ln1_b = (const float*)d_in[6];
  const float* Wq    = (const float*)d_in[7];
  const float* Wk    = (const float*)d_in[8];
  const float* Wv    = (const float*)d_in[9];
  const float* Wpx   = (const float*)d_in[10];
  const float* Wpy   = (const float*)d_in[11];
  const float* ln2_g = (const float*)d_in[12];
  const float* ln2_b = (const float*)d_in[13];
  const float* fx1_w = (const float*)d_in[14];
  const float* fx1_b = (const float*)d_in[15];
  const float* fx2_w = (const float*)d_in[16];
  const float* fx2_b = (const float*)d_in[17];
  const float* fy1_w = (const float*)d_in[18];
  const float* fy1_b = (const float*)d_in[19];
  const float* fy2_w = (const float*)d_in[20];
  const float* fy2_b = (const float*)d_in[21];

  float* out    = (float*)d_out;
  float* out_xo = out;
  float* out_yo = out + (size_t)M_*C_;
  float* out_ps = out + 2*(size_t)M_*C_;

  char* ws = (char*)d_ws;
  const size_t ACT = (size_t)M_*C_;        // 25165824 elems
  u16* R0  = (u16*)ws;
  u16* xnb = R0;                           // slot0: xn bf16 (later: x bf16)
  u16* ynb = R0 + ACT;                     // slot1: yn bf16 (later: y bf16)
  u16* kb  = R0 + 2*ACT;                   // slot2: k bf16
  // slot3 free (v eliminated)
  u16* hid = R0;                           // MLP hidden bf16 [M,H] aliases slots 0-3
  u16* qb  = (u16*)(ws + 4*ACT*2);         // slot4: ln2 out bf16
  u16* wp  = (u16*)(ws + 5*ACT*2);         // bf16 weights (transposed)
  u16* WkT  = wp;
  u16* WpxT = wp + 1*589824;
  u16* WpyT = wp + 2*589824;
  u16* fx1T = wp + 3*589824;
  u16* fx2T = fx1T + 2359296;
  u16* fy1T = fx2T + 2359296;
  u16* fy2T = fy1T + 2359296;
  float* st   = (float*)(ws + 5*ACT*2 + (size_t)(3*589824 + 4*2359296)*2);
  float* msum = st;             // 8
  float* fgn  = st + 8;         // 8
  float* bgn  = st + 16;        // 8
  float* denom= st + 24;        // 8
  float* mm   = st + 32;        // 32
  float* fg   = st + 64;        // 6144
  float* bg   = st + 6208;      // 6144
  float* qp   = st + 12352;     // 6144
  float* pro  = st + 18496;     // 6144
  float* rowx = st + 24640;     // 6144
  float* rowy = st + 30784;     // 6144
  float* epart= st + 36928;     // 128
  float* fg_s = st + 37056;     // 32768
  float* bg_s = st + 69824;     // 32768
  float* escr = st + 102592;    // 32768
  float* pm   = st + 135360;    // 98304
  float* pa   = st + 233664;    // 98304
  float* pv   = st + 331968;    // 98304
  float* fgin = st + 430272;    // 6144
  float* bgin = st + 436416;    // 6144
  float* vpin = st + 442560;    // 6144

  dim3 tb(256);

  // --- weights -> bf16, transposed to [N,K] (only GEMM operands) ---
  transpose_cvt<<<dim3(24,24),tb,0,stream>>>(Wk,  WkT,  C_, C_);
  transpose_cvt<<<dim3(24,24),tb,0,stream>>>(Wpx, WpxT, C_, C_);
  transpose_cvt<<<dim3(24,24),tb,0,stream>>>(Wpy, WpyT, C_, C_);
  transpose_cvt<<<dim3(96,24),tb,0,stream>>>(fx1_w, fx1T, C_, H_);
  transpose_cvt<<<dim3(24,96),tb,0,stream>>>(fx2_w, fx2T, H_, C_);
  transpose_cvt<<<dim3(96,24),tb,0,stream>>>(fy1_w, fy1T, C_, H_);
  transpose_cvt<<<dim3(24,96),tb,0,stream>>>(fy2_w, fy2T, H_, C_);

  // --- LN1 ---
  ln_fwd<<<M_/4,tb,0,stream>>>(x, ln1_g, ln1_b, xnb);
  ln_fwd<<<M_/4,tb,0,stream>>>(y, ln1_g, ln1_b, ynb);

  // --- k GEMM (q,v eliminated by pooling linearity) ---
  gemm_bf16<0><<<dim3(256*6),tb,0,stream>>>(xnb, WkT, C_, C_, 6, kb, nullptr,nullptr,nullptr);

  // --- pooled prototypes: fg = pooled(m*yn)@Wq / msum (f32), bg analog ---
  msum_kernel<<<B_,tb,0,stream>>>(mask, msum);
  pool_partial<<<dim3(3,B_,NSPLIT),tb,0,stream>>>(ynb, mask, pm, pa);
  pool_final<<<dim3(3,B_),tb,0,stream>>>(pm, pa, msum, fgin, bgin);
  vecmat2<<<dim3(3,B_),tb,0,stream>>>(fgin, bgin, Wq, fg, bg);
  norm_kernel<<<B_,tb,0,stream>>>(fg, bg, fgn, bgn);

  // --- cosine scores + softmax weights ---
  score_kernel<<<M_,tb,0,stream>>>(kb, fg, bg, fgn, bgn, fg_s, bg_s);
  minmax_kernel<<<B_,tb,0,stream>>>(fg_s, bg_s, mm);
  scorefin_kernel<<<dim3(16,B_),tb,0,stream>>>(fg_s, bg_s, mm, out_ps, escr, epart);
  denom_kernel<<<1,64,0,stream>>>(epart, denom);

  // --- query_pro = (attn-pooled xn) @ Wv  (v GEMM eliminated) ---
  vpool_partial<<<dim3(3,B_,NSPLIT),tb,0,stream>>>(xnb, escr, pv);
  vpool_final<<<dim3(3,B_),tb,0,stream>>>(pv, denom, vpin);
  vecmat<<<dim3(3,B_),tb,0,stream>>>(vpin, Wv, 0, qp);

  pro_kernel<<<B_,tb,0,stream>>>(qp, fg, fgn, pro);
  vecmat<<<dim3(3,B_),tb,0,stream>>>(pro, Wpx, C_, rowx);
  vecmat<<<dim3(3,B_),tb,0,stream>>>(pro, Wpy, C_, rowy);

  // --- x,y -> bf16 (xnb dead after vpool_partial, ynb dead after pool_partial) ---
  cvt_bf16<<<(ACT/4+255)/256,tb,0,stream>>>(x, xnb, (int)(ACT/4));
  cvt_bf16<<<(ACT/4+255)/256,tb,0,stream>>>(y, ynb, (int)(ACT/4));

  // --- projection GEMMs: out = resid + act@WpA + pro@WpB ---
  gemm_bf16<1><<<dim3(256*6),tb,0,stream>>>(xnb, WpxT, C_, C_, 6, out_xo, x, rowx, nullptr);
  gemm_bf16<1><<<dim3(256*6),tb,0,stream>>>(ynb, WpyT, C_, C_, 6, out_yo, y, rowy, nullptr);

  // --- x MLP ---
  ln_fwd<<<M_/4,tb,0,stream>>>(out_xo, ln2_g, ln2_b, qb);
  gemm_bf16<2><<<dim3(256*24),tb,0,stream>>>(qb, fx1T, C_, H_, 24, hid, nullptr,nullptr, fx1_b);
  gemm_bf16<3><<<dim3(256*6),tb,0,stream>>>(hid, fx2T, H_, C_, 6, out_xo, nullptr,nullptr, fx2_b);

  // --- y MLP ---
  ln_fwd<<<M_/4,tb,0,stream>>>(out_yo, ln2_g, ln2_b, qb);
  gemm_bf16<2><<<dim3(256*24),tb,0,stream>>>(qb, fy1T, C_, H_, 24, hid, nullptr,nullptr, fy1_b);
  gemm_bf16<3><<<dim3(256*6),tb,0,stream>>>(hid, fy2T, H_, C_, 6, out_yo, nullptr,nullptr, fy2_b);
}

// Round 5
// 1620.603 us; speedup vs baseline: 1.1691x; 1.1512x over previous
//
#include <hip/hip_runtime.h>
#include <math.h>

#define B_ 8
#define N_ 4096
#define C_ 768
#define H_ 3072
#define M_ (B_*N_)
#define NSPLIT 16

typedef unsigned short u16;
typedef unsigned int u32;
typedef __attribute__((ext_vector_type(8))) __bf16 bf16x8;
typedef __attribute__((ext_vector_type(4))) float f32x4;
typedef __attribute__((ext_vector_type(4))) unsigned short u16x4;
typedef __attribute__((ext_vector_type(8))) unsigned short u16x8;

__device__ __forceinline__ u16 f2bf(float f){
  u32 u = __float_as_uint(f);
  u32 r = (u + 0x7FFFu + ((u >> 16) & 1u)) >> 16;
  return (u16)r;
}
__device__ __forceinline__ float bf2f(u16 h){
  return __uint_as_float(((u32)h) << 16);
}
__device__ __forceinline__ void gload_lds16(const void* g, void* l){
  __builtin_amdgcn_global_load_lds((const __attribute__((address_space(1))) void*)g,
                                   (__attribute__((address_space(3))) void*)l, 16, 0, 0);
}

// ---------------- GEMM: C[M,N] = A[M,K](bf16) * BT[N,K](bf16)^T ----------------
// 256x128 tile, 512 thr = 8 waves (4M x 2N), per-wave 64x64 = acc[4][4] of
// mfma_f32_16x16x32_bf16 (64 VGPR acc -> 2 blocks/CU, 16 waves/CU).
// 2-phase pipeline: dbuf LDS, STAGE(next) before compute(cur), 1 barrier/K-iter.
// LDS/buf: A[256][32] (16KB) + B[128][32] (8KB) = 24KB, x2 = 48KB.
// EPI: 0=bf16 out; 1=f32 resid+acc+rowv; 2=bf16 gelu(acc+bias); 3=f32 +=acc+bias
template<int EPI>
__global__ __launch_bounds__(512, 4) void gemm_bf16(
    const u16* __restrict__ A, const u16* __restrict__ BT,
    int K, int N, int NBN,
    void* __restrict__ outp,
    const float* __restrict__ resid,
    const float* __restrict__ rowv,
    const float* __restrict__ bias)
{
  __shared__ u16 lds[2][12288];
  const int tid = threadIdx.x;
  const int wid = tid >> 6, lane = tid & 63;

  // block swizzle: XCD chunk (nwg%8==0) + GM=8 row-panel grouping
  const int nwg = gridDim.x;
  int wg = blockIdx.x;
  wg = (wg & 7) * (nwg >> 3) + (wg >> 3);
  const int GMN = 8 * NBN;
  const int g = wg / GMN, r = wg % GMN;
  const int bm = (g*8 + (r & 7)) * 256;
  const int bn = (r >> 3) * 128;

  const int wr = wid >> 1, wc = wid & 1;

  f32x4 acc[4][4];
#pragma unroll
  for (int i=0;i<4;i++)
#pragma unroll
    for (int j=0;j<4;j++) acc[i][j] = (f32x4){0.f,0.f,0.f,0.f};

  const u16* agp0 = A  + (size_t)(bm + (tid>>2))*K + (tid&3)*8;
  const u16* agp1 = A  + (size_t)(bm + 128 + (tid>>2))*K + (tid&3)*8;
  const u16* bgp0 = BT + (size_t)(bn + (tid>>2))*K + (tid&3)*8;

  auto STAGE = [&](int c){
    char* base = (char*)lds[c] + wid*1024;   // wave-uniform LDS base; HW adds lane*16
    gload_lds16(agp0, base);
    gload_lds16(agp1, base + 8192);
    gload_lds16(bgp0, base + 16384);
    agp0 += 32; agp1 += 32; bgp0 += 32;
  };

  const int aoff = (wr*64 + (lane&15))*32 + ((lane>>4)<<3);
  const int boff = 8192 + (wc*64 + (lane&15))*32 + ((lane>>4)<<3);

  const int nk = K >> 5;
  STAGE(0);
  __syncthreads();
  int cur = 0;
  for (int kk=0; kk<nk; kk++){
    if (kk+1 < nk) STAGE(cur^1);   // overlap next-tile HBM latency with compute
    bf16x8 av[4], bv[4];
    const u16* pa = &lds[cur][aoff];
    const u16* pb = &lds[cur][boff];
#pragma unroll
    for (int i=0;i<4;i++){
      av[i] = *reinterpret_cast<const bf16x8*>(pa + i*512);
      bv[i] = *reinterpret_cast<const bf16x8*>(pb + i*512);
    }
#pragma unroll
    for (int i=0;i<4;i++)
#pragma unroll
      for (int j=0;j<4;j++)
        acc[i][j] = __builtin_amdgcn_mfma_f32_16x16x32_bf16(av[i], bv[j], acc[i][j], 0, 0, 0);
    __syncthreads();
    cur ^= 1;
  }

  // C/D layout (verified m89): col = lane&15, row = (lane>>4)*4 + r
  const int col0 = bn + wc*64 + (lane & 15);
  const int row0 = bm + wr*64 + ((lane >> 4) << 2);
#pragma unroll
  for (int i=0;i<4;i++){
#pragma unroll
    for (int j=0;j<4;j++){
#pragma unroll
      for (int r2=0;r2<4;r2++){
        const int row = row0 + i*16 + r2;
        const int cj  = col0 + j*16;
        const size_t o = (size_t)row*N + cj;
        const float va = acc[i][j][r2];
        if constexpr (EPI == 0){
          ((u16*)outp)[o] = f2bf(va);
        } else if constexpr (EPI == 1){
          ((float*)outp)[o] = resid[o] + va + rowv[(row >> 12)*N + cj];
        } else if constexpr (EPI == 2){
          const float z = va + bias[cj];
          ((u16*)outp)[o] = f2bf(0.5f*z*(1.0f + erff(z*0.70710678f)));
        } else {
          float* po = (float*)outp + o;
          *po += va + bias[cj];
        }
      }
    }
  }
}

// ---------------- LayerNorm over last dim (768): wave-per-row, float4 ----------------
__device__ __forceinline__ void ln_row(const float* __restrict__ p,
    const float* __restrict__ gam, const float* __restrict__ bet,
    u16* __restrict__ op, int lane)
{
  float4 v0 = *reinterpret_cast<const float4*>(p + lane*4);
  float4 v1 = *reinterpret_cast<const float4*>(p + lane*4 + 256);
  float4 v2 = *reinterpret_cast<const float4*>(p + lane*4 + 512);
  float s  = v0.x+v0.y+v0.z+v0.w + v1.x+v1.y+v1.z+v1.w + v2.x+v2.y+v2.z+v2.w;
  float sq = v0.x*v0.x+v0.y*v0.y+v0.z*v0.z+v0.w*v0.w
           + v1.x*v1.x+v1.y*v1.y+v1.z*v1.z+v1.w*v1.w
           + v2.x*v2.x+v2.y*v2.y+v2.z*v2.z+v2.w*v2.w;
#pragma unroll
  for (int o=32;o>0;o>>=1){ s += __shfl_xor(s,o); sq += __shfl_xor(sq,o); }
  const float mu = s * (1.f/C_);
  const float rs = rsqrtf(sq*(1.f/C_) - mu*mu + 1e-5f);
  float4 g0 = *reinterpret_cast<const float4*>(gam + lane*4);
  float4 g1 = *reinterpret_cast<const float4*>(gam + lane*4 + 256);
  float4 g2 = *reinterpret_cast<const float4*>(gam + lane*4 + 512);
  float4 b0 = *reinterpret_cast<const float4*>(bet + lane*4);
  float4 b1 = *reinterpret_cast<const float4*>(bet + lane*4 + 256);
  float4 b2 = *reinterpret_cast<const float4*>(bet + lane*4 + 512);
  u16x4 o0, o1, o2;
  o0[0]=f2bf((v0.x-mu)*rs*g0.x+b0.x); o0[1]=f2bf((v0.y-mu)*rs*g0.y+b0.y);
  o0[2]=f2bf((v0.z-mu)*rs*g0.z+b0.z); o0[3]=f2bf((v0.w-mu)*rs*g0.w+b0.w);
  o1[0]=f2bf((v1.x-mu)*rs*g1.x+b1.x); o1[1]=f2bf((v1.y-mu)*rs*g1.y+b1.y);
  o1[2]=f2bf((v1.z-mu)*rs*g1.z+b1.z); o1[3]=f2bf((v1.w-mu)*rs*g1.w+b1.w);
  o2[0]=f2bf((v2.x-mu)*rs*g2.x+b2.x); o2[1]=f2bf((v2.y-mu)*rs*g2.y+b2.y);
  o2[2]=f2bf((v2.z-mu)*rs*g2.z+b2.z); o2[3]=f2bf((v2.w-mu)*rs*g2.w+b2.w);
  *reinterpret_cast<u16x4*>(op + lane*4)       = o0;
  *reinterpret_cast<u16x4*>(op + lane*4 + 256) = o1;
  *reinterpret_cast<u16x4*>(op + lane*4 + 512) = o2;
}

__global__ __launch_bounds__(256) void ln_fwd(const float* __restrict__ in,
    const float* __restrict__ gam, const float* __restrict__ bet,
    u16* __restrict__ out)
{
  const int row  = blockIdx.x*4 + (threadIdx.x >> 6);
  const int lane = threadIdx.x & 63;
  ln_row(in + (size_t)row*C_, gam, bet, out + (size_t)row*C_, lane);
}

// fused LN1 for x and y (z-dim selects input)
__global__ __launch_bounds__(256) void ln_fwd2(const float* __restrict__ inx,
    const float* __restrict__ iny, const float* __restrict__ gam,
    const float* __restrict__ bet, u16* __restrict__ outx, u16* __restrict__ outy)
{
  const int row  = blockIdx.x*4 + (threadIdx.x >> 6);
  const int lane = threadIdx.x & 63;
  const float* in = blockIdx.y ? iny : inx;
  u16* out = blockIdx.y ? outy : outx;
  ln_row(in + (size_t)row*C_, gam, bet, out + (size_t)row*C_, lane);
}

// ---------------- f32 -> bf16 convert, x and y in one launch ----------------
__global__ __launch_bounds__(256) void cvt2_bf16(const float* __restrict__ inx,
    const float* __restrict__ iny, u16* __restrict__ outx, u16* __restrict__ outy,
    int n4)
{
  int i = blockIdx.x*256 + threadIdx.x;
  const float* in = blockIdx.y ? iny : inx;
  u16* out = blockIdx.y ? outy : outx;
  if (i < n4){
    float4 v = reinterpret_cast<const float4*>(in)[i];
    u16x4 o; o[0]=f2bf(v.x); o[1]=f2bf(v.y); o[2]=f2bf(v.z); o[3]=f2bf(v.w);
    *reinterpret_cast<u16x4*>(out + (size_t)i*4) = o;
  }
}

// ---------------- all 7 weight transposes in one launch ----------------
__device__ __forceinline__ void tr_tile(const float* __restrict__ in,
    u16* __restrict__ outp, int R, int Cc, int t)
{
  __shared__ float tile[32][33];
  const int tilesx = Cc >> 5;
  const int c0 = (t % tilesx)*32, r0 = (t / tilesx)*32;
  const int tx = threadIdx.x & 31, ty = threadIdx.x >> 5;
#pragma unroll
  for (int i=0;i<32;i+=8)
    tile[ty+i][tx] = in[(size_t)(r0+ty+i)*Cc + c0+tx];
  __syncthreads();
#pragma unroll
  for (int i=0;i<32;i+=8)
    outp[(size_t)(c0+ty+i)*R + r0+tx] = f2bf(tile[tx][ty+i]);
}

__global__ __launch_bounds__(256) void transpose_all(
    const float* Wk, const float* Wpx, const float* Wpy,
    const float* f1x, const float* f2x, const float* f1y, const float* f2y,
    u16* WkT, u16* WpxT, u16* WpyT, u16* f1xT, u16* f2xT, u16* f1yT, u16* f2yT)
{
  int t = blockIdx.x;
  if (t < 1728){
    const int m = t / 576; t -= m*576;
    const float* in = (m==0)?Wk:((m==1)?Wpx:Wpy);
    u16* o = (m==0)?WkT:((m==1)?WpxT:WpyT);
    tr_tile(in, o, C_, C_, t);
  } else {
    t -= 1728;
    const int m = t / 2304; t -= m*2304;
    if (m==0)      tr_tile(f1x, f1xT, C_, H_, t);
    else if (m==1) tr_tile(f2x, f2xT, H_, C_, t);
    else if (m==2) tr_tile(f1y, f1yT, C_, H_, t);
    else           tr_tile(f2y, f2yT, H_, C_, t);
  }
}

// ---------------- masked pooling partials of yn (+ mask partial) ----------------
__global__ __launch_bounds__(256) void pool_partial(const u16* __restrict__ q,
    const float* __restrict__ mask, float* __restrict__ pm, float* __restrict__ pa,
    float* __restrict__ mpart)
{
  const int c = blockIdx.x*256 + threadIdx.x;
  const int b = blockIdx.y, z = blockIdx.z;
  const int n0 = z*(N_/NSPLIT);
  const u16* qp = q + ((size_t)b*N_ + n0)*C_ + c;
  const float* mp = mask + (size_t)b*N_ + n0;
  float am=0.f, aa=0.f, ms=0.f;
  for (int n=0;n<N_/NSPLIT;n++){
    float v = bf2f(qp[(size_t)n*C_]);
    float m = mp[n];
    am += v*m; aa += v; ms += m;
  }
  const size_t o = ((size_t)z*B_ + b)*C_ + c;
  pm[o]=am; pa[o]=aa;
  if (blockIdx.x==0 && threadIdx.x==0) mpart[z*B_+b] = ms;
}

// ---------------- proto_fused: pool_final + (fg,bg)=pooled@Wq + norms ----------------
// one block per b, 256 threads
__global__ __launch_bounds__(256) void proto_fused(const float* __restrict__ pm,
    const float* __restrict__ pa, const float* __restrict__ mpart,
    const float* __restrict__ Wq,
    float* __restrict__ fg, float* __restrict__ bg,
    float* __restrict__ fgn, float* __restrict__ bgn)
{
  __shared__ float fin[C_], bin[C_];
  __shared__ float red[8];
  const int b = blockIdx.x, tid = threadIdx.x;
  float msum_b = 0.f;
#pragma unroll
  for (int z=0;z<NSPLIT;z++) msum_b += mpart[z*B_+b];
  for (int c=tid;c<C_;c+=256){
    float sm=0.f, sa=0.f;
#pragma unroll
    for (int z=0;z<NSPLIT;z++){ size_t o=((size_t)z*B_+b)*C_+c; sm+=pm[o]; sa+=pa[o]; }
    fin[c] = sm/(msum_b + 5e-4f);
    bin[c] = (sa - sm)/((float)N_ - msum_b + 5e-4f);
  }
  __syncthreads();
  const int j0 = tid, j1 = tid+256, j2 = tid+512;
  float f0=0,f1=0,f2=0,g0=0,g1=0,g2=0;
  for (int c=0;c<C_;c++){
    const float* w = Wq + (size_t)c*C_;
    float fc = fin[c], bc = bin[c];
    float w0=w[j0], w1=w[j1], w2=w[j2];
    f0 += fc*w0; f1 += fc*w1; f2 += fc*w2;
    g0 += bc*w0; g1 += bc*w1; g2 += bc*w2;
  }
  fg[b*C_+j0]=f0; fg[b*C_+j1]=f1; fg[b*C_+j2]=f2;
  bg[b*C_+j0]=g0; bg[b*C_+j1]=g1; bg[b*C_+j2]=g2;
  float sf = f0*f0+f1*f1+f2*f2, sb = g0*g0+g1*g1+g2*g2;
#pragma unroll
  for (int o=32;o>0;o>>=1){ sf+=__shfl_down(sf,o); sb+=__shfl_down(sb,o); }
  if ((tid&63)==0){ red[tid>>6]=sf; red[4+(tid>>6)]=sb; }
  __syncthreads();
  if (tid==0){
    fgn[b]=sqrtf(red[0]+red[1]+red[2]+red[3]);
    bgn[b]=sqrtf(red[4]+red[5]+red[6]+red[7]);
  }
}

// ---------------- cosine scores: wave-per-token ----------------
__global__ __launch_bounds__(256) void score_kernel(const u16* __restrict__ k,
    const float* __restrict__ fg, const float* __restrict__ bg,
    const float* __restrict__ fgn, const float* __restrict__ bgn,
    float* __restrict__ fg_s, float* __restrict__ bg_s)
{
  const int t = blockIdx.x*4 + (threadIdx.x >> 6);
  const int lane = threadIdx.x & 63;
  const int b = t >> 12;
  const u16* kp = k + (size_t)t*C_;
  u16x8 k8 = *reinterpret_cast<const u16x8*>(kp + lane*8);
  u16x4 k4 = *reinterpret_cast<const u16x4*>(kp + 512 + lane*4);
  const float* fgp = fg + b*C_;
  const float* bgp = bg + b*C_;
  float4 fa = *reinterpret_cast<const float4*>(fgp + lane*8);
  float4 fb = *reinterpret_cast<const float4*>(fgp + lane*8 + 4);
  float4 fc = *reinterpret_cast<const float4*>(fgp + 512 + lane*4);
  float4 ba = *reinterpret_cast<const float4*>(bgp + lane*8);
  float4 bb = *reinterpret_cast<const float4*>(bgp + lane*8 + 4);
  float4 bc = *reinterpret_cast<const float4*>(bgp + 512 + lane*4);
  float kv[12];
#pragma unroll
  for (int i=0;i<8;i++) kv[i] = bf2f(k8[i]);
#pragma unroll
  for (int i=0;i<4;i++) kv[8+i] = bf2f(k4[i]);
  float df = kv[0]*fa.x+kv[1]*fa.y+kv[2]*fa.z+kv[3]*fa.w
           + kv[4]*fb.x+kv[5]*fb.y+kv[6]*fb.z+kv[7]*fb.w
           + kv[8]*fc.x+kv[9]*fc.y+kv[10]*fc.z+kv[11]*fc.w;
  float db = kv[0]*ba.x+kv[1]*ba.y+kv[2]*ba.z+kv[3]*ba.w
           + kv[4]*bb.x+kv[5]*bb.y+kv[6]*bb.z+kv[7]*bb.w
           + kv[8]*bc.x+kv[9]*bc.y+kv[10]*bc.z+kv[11]*bc.w;
  float kk=0.f;
#pragma unroll
  for (int i=0;i<12;i++) kk += kv[i]*kv[i];
#pragma unroll
  for (int o=32;o>0;o>>=1){
    df+=__shfl_xor(df,o); db+=__shfl_xor(db,o); kk+=__shfl_xor(kk,o);
  }
  if (lane==0){
    const float kn = sqrtf(kk);
    fg_s[t] = df/(kn*fgn[b]+1e-7f);
    bg_s[t] = db/(kn*bgn[b]+1e-7f);
  }
}

__global__ __launch_bounds__(256) void minmax_kernel(const float* __restrict__ fg_s,
    const float* __restrict__ bg_s, float* __restrict__ mm)
{
  __shared__ float sm[16];
  const int b = blockIdx.x;
  float mnf=1e30f, mxf=-1e30f, mnb=1e30f, mxb=-1e30f;
  for (int i=threadIdx.x;i<N_;i+=256){
    float a = fg_s[(size_t)b*N_+i]; mnf=fminf(mnf,a); mxf=fmaxf(mxf,a);
    float c = bg_s[(size_t)b*N_+i]; mnb=fminf(mnb,c); mxb=fmaxf(mxb,c);
  }
#pragma unroll
  for (int o=32;o>0;o>>=1){
    mnf=fminf(mnf,__shfl_down(mnf,o)); mxf=fmaxf(mxf,__shfl_down(mxf,o));
    mnb=fminf(mnb,__shfl_down(mnb,o)); mxb=fmaxf(mxb,__shfl_down(mxb,o));
  }
  const int wid = threadIdx.x>>6;
  if ((threadIdx.x&63)==0){ sm[wid]=mnf; sm[4+wid]=mxf; sm[8+wid]=mnb; sm[12+wid]=mxb; }
  __syncthreads();
  if (threadIdx.x==0){
    mm[b*4+0]=fminf(fminf(sm[0],sm[1]),fminf(sm[2],sm[3]));
    mm[b*4+1]=fmaxf(fmaxf(sm[4],sm[5]),fmaxf(sm[6],sm[7]));
    mm[b*4+2]=fminf(fminf(sm[8],sm[9]),fminf(sm[10],sm[11]));
    mm[b*4+3]=fmaxf(fmaxf(sm[12],sm[13]),fmaxf(sm[14],sm[15]));
  }
}

// scores -> pseudo out + exp weights + denom, one block per b (1024 thr)
__global__ __launch_bounds__(1024) void scorefin_fused(const float* __restrict__ fg_s,
    const float* __restrict__ bg_s, const float* __restrict__ mm,
    float* __restrict__ pseudo, float* __restrict__ escr, float* __restrict__ denom)
{
  __shared__ float sm[16];
  const int b = blockIdx.x, tid = threadIdx.x;
  const float mnf=mm[b*4+0], mxf=mm[b*4+1], mnb=mm[b*4+2], mxb=mm[b*4+3];
  const float rf = 1.f/(mxf-mnf+1e-7f), rb = 1.f/(mxb-mnb+1e-7f);
  float ps = 0.f;
#pragma unroll
  for (int i=0;i<4;i++){
    const int t = tid + i*1024;
    const size_t o = (size_t)b*N_ + t;
    const float s = (fg_s[o]-mnf)*rf - (bg_s[o]-mnb)*rb;
    pseudo[o] = s;
    const float e = expf(s < 0.f ? s - 100.f : s);
    escr[o] = e;
    ps += e;
  }
#pragma unroll
  for (int o=32;o>0;o>>=1) ps += __shfl_down(ps,o);
  if ((tid&63)==0) sm[tid>>6]=ps;
  __syncthreads();
  if (tid==0){
    float s=0.f;
#pragma unroll
    for (int w=0;w<16;w++) s+=sm[w];
    denom[b]=s;
  }
}

// attn-pool partials of xn
__global__ __launch_bounds__(256) void vpool_partial(const u16* __restrict__ xn,
    const float* __restrict__ e, float* __restrict__ pv)
{
  const int c = blockIdx.x*256 + threadIdx.x;
  const int b = blockIdx.y, z = blockIdx.z;
  const int n0 = z*(N_/NSPLIT);
  const u16* vp = xn + ((size_t)b*N_ + n0)*C_ + c;
  const float* ep = e + (size_t)b*N_ + n0;
  float acc=0.f;
  for (int n=0;n<N_/NSPLIT;n++) acc += bf2f(vp[(size_t)n*C_])*ep[n];
  pv[((size_t)z*B_+b)*C_+c] = acc;
}

// pro_fused: vpool_final + qp=vin@Wv + sim + pro + rowx=pro@WpxB + rowy=pro@WpyB
// one block per b, 256 threads
__global__ __launch_bounds__(256) void pro_fused(const float* __restrict__ pv,
    const float* __restrict__ denom,
    const float* __restrict__ Wv, const float* __restrict__ Wpx,
    const float* __restrict__ Wpy,
    const float* __restrict__ fg, const float* __restrict__ fgn,
    float* __restrict__ rowx, float* __restrict__ rowy)
{
  __shared__ float vin[C_];
  __shared__ float red[8];
  __shared__ float simsh;
  const int b = blockIdx.x, tid = threadIdx.x;
  const float den = 1.f/denom[b];
  for (int c=tid;c<C_;c+=256){
    float s=0.f;
#pragma unroll
    for (int z=0;z<NSPLIT;z++) s += pv[((size_t)z*B_+b)*C_+c];
    vin[c] = s*den;
  }
  __syncthreads();
  const int j0 = tid, j1 = tid+256, j2 = tid+512;
  float q0=0,q1=0,q2=0;
  for (int c=0;c<C_;c++){
    const float* w = Wv + (size_t)c*C_;
    float vv = vin[c];
    q0 += vv*w[j0]; q1 += vv*w[j1]; q2 += vv*w[j2];
  }
  const float fg0 = fg[b*C_+j0], fg1 = fg[b*C_+j1], fg2 = fg[b*C_+j2];
  float d = q0*fg0 + q1*fg1 + q2*fg2;
  float qq = q0*q0 + q1*q1 + q2*q2;
#pragma unroll
  for (int o=32;o>0;o>>=1){ d+=__shfl_down(d,o); qq+=__shfl_down(qq,o); }
  if ((tid&63)==0){ red[tid>>6]=d; red[4+(tid>>6)]=qq; }
  __syncthreads();
  if (tid==0){
    float dd=red[0]+red[1]+red[2]+red[3], qs=red[4]+red[5]+red[6]+red[7];
    simsh = (dd/(sqrtf(qs)*fgn[b]+1e-7f)+1.f)*0.5f;
  }
  __syncthreads();
  const float sim = simsh;
  // overwrite vin with pro (all matvec reads of vin finished: barrier above)
  vin[j0] = sim*fg0 + (1.f-sim)*q0;
  vin[j1] = sim*fg1 + (1.f-sim)*q1;
  vin[j2] = sim*fg2 + (1.f-sim)*q2;
  __syncthreads();
  float rx0=0,rx1=0,rx2=0, ry0=0,ry1=0,ry2=0;
  for (int c=0;c<C_;c++){
    const float* wx = Wpx + (size_t)(C_+c)*C_;
    const float* wy = Wpy + (size_t)(C_+c)*C_;
    float pc = vin[c];
    rx0 += pc*wx[j0]; rx1 += pc*wx[j1]; rx2 += pc*wx[j2];
    ry0 += pc*wy[j0]; ry1 += pc*wy[j1]; ry2 += pc*wy[j2];
  }
  rowx[b*C_+j0]=rx0; rowx[b*C_+j1]=rx1; rowx[b*C_+j2]=rx2;
  rowy[b*C_+j0]=ry0; rowy[b*C_+j1]=ry1; rowy[b*C_+j2]=ry2;
}

// ---------------- launcher ----------------
extern "C" void kernel_launch(void* const* d_in, const int* in_sizes, int n_in,
                              void* d_out, int out_size, void* d_ws, size_t ws_size,
                              hipStream_t stream)
{
  const float* x     = (const float*)d_in[0];
  const float* y     = (const float*)d_in[1];
  const float* mask  = (const float*)d_in[2];
  const float* ln1_g = (const float*)d_in[5];
  const float* ln1_b = (const float*)d_in[6];
  const float* Wq    = (const float*)d_in[7];
  const float* Wk    = (const float*)d_in[8];
  const float* Wv    = (const float*)d_in[9];
  const float* Wpx   = (const float*)d_in[10];
  const float* Wpy   = (const float*)d_in[11];
  const float* ln2_g = (const float*)d_in[12];
  const float* ln2_b = (const float*)d_in[13];
  const float* fx1_w = (const float*)d_in[14];
  const float* fx1_b = (const float*)d_in[15];
  const float* fx2_w = (const float*)d_in[16];
  const float* fx2_b = (const float*)d_in[17];
  const float* fy1_w = (const float*)d_in[18];
  const float* fy1_b = (const float*)d_in[19];
  const float* fy2_w = (const float*)d_in[20];
  const float* fy2_b = (const float*)d_in[21];

  float* out    = (float*)d_out;
  float* out_xo = out;
  float* out_yo = out + (size_t)M_*C_;
  float* out_ps = out + 2*(size_t)M_*C_;

  char* ws = (char*)d_ws;
  const size_t ACT = (size_t)M_*C_;
  u16* R0  = (u16*)ws;
  u16* xnb = R0;                           // slot0: xn (later: x bf16)
  u16* ynb = R0 + ACT;                     // slot1: yn (later: y bf16)
  u16* kb  = R0 + 2*ACT;                   // slot2: k
  u16* hid = R0;                           // MLP hidden aliases slots 0-3
  u16* qb  = (u16*)(ws + 4*ACT*2);         // slot4: ln2 out
  u16* wp  = (u16*)(ws + 5*ACT*2);
  u16* WkT  = wp;
  u16* WpxT = wp + 1*589824;
  u16* WpyT = wp + 2*589824;
  u16* fx1T = wp + 3*589824;
  u16* fx2T = fx1T + 2359296;
  u16* fy1T = fx2T + 2359296;
  u16* fy2T = fy1T + 2359296;
  float* st   = (float*)(ws + 5*ACT*2 + (size_t)(3*589824 + 4*2359296)*2);
  float* fgn  = st + 8;
  float* bgn  = st + 16;
  float* denom= st + 24;
  float* mm   = st + 32;
  float* fg   = st + 64;
  float* bg   = st + 6208;
  float* rowx = st + 24640;
  float* rowy = st + 30784;
  float* fg_s = st + 37056;
  float* bg_s = st + 69824;
  float* escr = st + 102592;
  float* pm   = st + 135360;
  float* pa   = st + 233664;
  float* pv   = st + 331968;
  float* mpart= st + 430272;   // 128

  dim3 tb(256);
  dim3 tg(512);

  // --- weights -> bf16 [N,K] + LN1(x,y) ---
  transpose_all<<<dim3(10944),tb,0,stream>>>(Wk,Wpx,Wpy,fx1_w,fx2_w,fy1_w,fy2_w,
                                             WkT,WpxT,WpyT,fx1T,fx2T,fy1T,fy2T);
  ln_fwd2<<<dim3(M_/4,2),tb,0,stream>>>(x, y, ln1_g, ln1_b, xnb, ynb);

  // --- k GEMM (q,v eliminated by pooling linearity) ---
  gemm_bf16<0><<<dim3(128*6),tg,0,stream>>>(xnb, WkT, C_, C_, 6, kb, nullptr,nullptr,nullptr);

  // --- prototypes fg,bg (f32 path) ---
  pool_partial<<<dim3(3,B_,NSPLIT),tb,0,stream>>>(ynb, mask, pm, pa, mpart);
  proto_fused<<<B_,tb,0,stream>>>(pm, pa, mpart, Wq, fg, bg, fgn, bgn);

  // --- cosine scores + softmax weights ---
  score_kernel<<<M_/4,tb,0,stream>>>(kb, fg, bg, fgn, bgn, fg_s, bg_s);
  minmax_kernel<<<B_,tb,0,stream>>>(fg_s, bg_s, mm);
  scorefin_fused<<<B_,dim3(1024),0,stream>>>(fg_s, bg_s, mm, out_ps, escr, denom);

  // --- query_pro path + pro + row-vectors ---
  vpool_partial<<<dim3(3,B_,NSPLIT),tb,0,stream>>>(xnb, escr, pv);
  pro_fused<<<B_,tb,0,stream>>>(pv, denom, Wv, Wpx, Wpy, fg, fgn, rowx, rowy);

  // --- x,y -> bf16 (xn/yn dead now) ---
  cvt2_bf16<<<dim3((ACT/4+255)/256,2),tb,0,stream>>>(x, y, xnb, ynb, (int)(ACT/4));

  // --- projection GEMMs: out = resid + act@WpA + pro@WpB ---
  gemm_bf16<1><<<dim3(128*6),tg,0,stream>>>(xnb, WpxT, C_, C_, 6, out_xo, x, rowx, nullptr);
  gemm_bf16<1><<<dim3(128*6),tg,0,stream>>>(ynb, WpyT, C_, C_, 6, out_yo, y, rowy, nullptr);

  // --- x MLP ---
  ln_fwd<<<M_/4,tb,0,stream>>>(out_xo, ln2_g, ln2_b, qb);
  gemm_bf16<2><<<dim3(128*24),tg,0,stream>>>(qb, fx1T, C_, H_, 24, hid, nullptr,nullptr, fx1_b);
  gemm_bf16<3><<<dim3(128*6),tg,0,stream>>>(hid, fx2T, H_, C_, 6, out_xo, nullptr,nullptr, fx2_b);

  // --- y MLP ---
  ln_fwd<<<M_/4,tb,0,stream>>>(out_yo, ln2_g, ln2_b, qb);
  gemm_bf16<2><<<dim3(128*24),tg,0,stream>>>(qb, fy1T, C_, H_, 24, hid, nullptr,nullptr, fy1_b);
  gemm_bf16<3><<<dim3(128*6),tg,0,stream>>>(hid, fy2T, H_, C_, 6, out_yo, nullptr,nullptr, fy2_b);
}

// Round 6
// 1527.669 us; speedup vs baseline: 1.2403x; 1.0608x over previous
//
#include <hip/hip_runtime.h>
#include <math.h>

#define B_ 8
#define N_ 4096
#define C_ 768
#define H_ 3072
#define M_ (B_*N_)
#define NSPLIT 16

typedef unsigned short u16;
typedef unsigned int u32;
typedef __attribute__((ext_vector_type(8))) __bf16 bf16x8;
typedef __attribute__((ext_vector_type(4))) float f32x4;
typedef __attribute__((ext_vector_type(4))) unsigned short u16x4;
typedef __attribute__((ext_vector_type(8))) unsigned short u16x8;

__device__ __forceinline__ u16 f2bf(float f){
  u32 u = __float_as_uint(f);
  u32 r = (u + 0x7FFFu + ((u >> 16) & 1u)) >> 16;
  return (u16)r;
}
__device__ __forceinline__ float bf2f(u16 h){
  return __uint_as_float(((u32)h) << 16);
}
__device__ __forceinline__ void gload_lds16(const void* g, void* l){
  __builtin_amdgcn_global_load_lds((const __attribute__((address_space(1))) void*)g,
                                   (__attribute__((address_space(3))) void*)l, 16, 0, 0);
}

// ---------------- GEMM: C[M,N] = A[M,K](bf16) * BT[N,K](bf16)^T ----------------
// 256x128 tile, 512 thr = 8 waves (4M x 2N), per-wave 64x64 = acc[4][4].
// TRIPLE-buffered LDS, 2-deep prefetch, counted s_waitcnt vmcnt(3) (T4):
//   prologue: STAGE(t0), STAGE(t1)        [6 loads in flight]
//   iter kk : vmcnt(3) -> tile kk landed; s_barrier (readers of buf[(kk-1)%3]
//             done); STAGE(kk+2 -> buf[(kk-1)%3]); compute buf[kk%3].
//   last iter uses vmcnt(0).
// LDS XOR swizzle (both-sides, rule #21): phys16Bchunk = logical ^ ((row>>1)&3);
// source pre-swizzled at global load, reads use (q ^ swz). Residual 2-way = free.
// LDS: 3 x (A 16KB + B 8KB) = 72KB -> 2 blocks/CU, 16 waves/CU.
// EPI: 0=bf16 out; 1=f32 resid+acc+rowv; 2=bf16 gelu(acc+bias); 3=f32 +=acc+bias
template<int EPI>
__global__ __launch_bounds__(512, 4) void gemm_bf16(
    const u16* __restrict__ A, const u16* __restrict__ BT,
    int K, int N, int NBN,
    void* __restrict__ outp,
    const float* __restrict__ resid,
    const float* __restrict__ rowv,
    const float* __restrict__ bias)
{
  __shared__ u16 lds[3][12288];
  const int tid = threadIdx.x;
  const int wid = tid >> 6, lane = tid & 63;

  // block swizzle: XCD chunk (nwg%8==0) + GM=8 row-panel grouping
  const int nwg = gridDim.x;
  int wg = blockIdx.x;
  wg = (wg & 7) * (nwg >> 3) + (wg >> 3);
  const int GMN = 8 * NBN;
  const int g = wg / GMN, r = wg % GMN;
  const int bm = (g*8 + (r & 7)) * 256;
  const int bn = (r >> 3) * 128;

  const int wr = wid >> 1, wc = wid & 1;
  const int l15 = lane & 15;

  f32x4 acc[4][4];
#pragma unroll
  for (int i=0;i<4;i++)
#pragma unroll
    for (int j=0;j<4;j++) acc[i][j] = (f32x4){0.f,0.f,0.f,0.f};

  // staging: slot tid -> row tid>>2, phys chunk tid&3; logical chunk pre-swizzled
  const int srow = tid >> 2;
  const int lchq = (tid & 3) ^ ((tid >> 3) & 3);     // (tid&3) ^ ((srow>>1)&3)
  const u16* agp0 = A  + (size_t)(bm + srow)*K       + lchq*8;
  const u16* agp1 = A  + (size_t)(bm + 128 + srow)*K + lchq*8;
  const u16* bgp0 = BT + (size_t)(bn + srow)*K       + lchq*8;

  auto STAGE = [&](int bi){
    char* base = (char*)lds[bi] + wid*1024;   // wave-uniform base; HW adds lane*16
    gload_lds16(agp0, base);
    gload_lds16(agp1, base + 8192);
    gload_lds16(bgp0, base + 16384);
    agp0 += 32; agp1 += 32; bgp0 += 32;
  };

  // swizzled read offsets (u16 units); swz invariant across i (row step 16)
  const int arow = wr*64 + l15;
  const int brow = wc*64 + l15;
  const int aswz = (arow >> 1) & 3;
  const int bswz = (brow >> 1) & 3;
  const int aoff = arow*32 + (((lane>>4) ^ aswz) << 3);
  const int boff = 8192 + brow*32 + (((lane>>4) ^ bswz) << 3);

  const int nk = K >> 5;
  STAGE(0);
  STAGE(1);
  int cb = 0;   // buffer holding tile kk
  for (int kk=0; kk<nk; kk++){
    if (kk == nk-1){ asm volatile("s_waitcnt vmcnt(0)" ::: "memory"); }
    else           { asm volatile("s_waitcnt vmcnt(3)" ::: "memory"); }
    __builtin_amdgcn_s_barrier();
    __builtin_amdgcn_sched_barrier(0);
    if (kk+2 < nk) STAGE(cb==0 ? 2 : cb-1);   // buf (kk+2)%3 == (kk-1)%3
    bf16x8 av[4], bv[4];
    const u16* pa = &lds[cb][aoff];
    const u16* pb = &lds[cb][boff];
#pragma unroll
    for (int i=0;i<4;i++){
      av[i] = *reinterpret_cast<const bf16x8*>(pa + i*512);
      bv[i] = *reinterpret_cast<const bf16x8*>(pb + i*512);
    }
#pragma unroll
    for (int i=0;i<4;i++)
#pragma unroll
      for (int j=0;j<4;j++)
        acc[i][j] = __builtin_amdgcn_mfma_f32_16x16x32_bf16(av[i], bv[j], acc[i][j], 0, 0, 0);
    cb = (cb==2) ? 0 : cb+1;
  }

  // C/D layout (verified m89): col = lane&15, row = (lane>>4)*4 + r
  const int col0 = bn + wc*64 + l15;
  const int row0 = bm + wr*64 + ((lane >> 4) << 2);
#pragma unroll
  for (int i=0;i<4;i++){
#pragma unroll
    for (int j=0;j<4;j++){
#pragma unroll
      for (int r2=0;r2<4;r2++){
        const int row = row0 + i*16 + r2;
        const int cj  = col0 + j*16;
        const size_t o = (size_t)row*N + cj;
        const float va = acc[i][j][r2];
        if constexpr (EPI == 0){
          ((u16*)outp)[o] = f2bf(va);
        } else if constexpr (EPI == 1){
          ((float*)outp)[o] = resid[o] + va + rowv[(row >> 12)*N + cj];
        } else if constexpr (EPI == 2){
          const float z = va + bias[cj];
          ((u16*)outp)[o] = f2bf(0.5f*z*(1.0f + erff(z*0.70710678f)));
        } else {
          float* po = (float*)outp + o;
          *po += va + bias[cj];
        }
      }
    }
  }
}

// ---------------- LayerNorm over last dim (768): wave-per-row, float4 ----------------
__device__ __forceinline__ void ln_row(const float* __restrict__ p,
    const float* __restrict__ gam, const float* __restrict__ bet,
    u16* __restrict__ op, int lane)
{
  float4 v0 = *reinterpret_cast<const float4*>(p + lane*4);
  float4 v1 = *reinterpret_cast<const float4*>(p + lane*4 + 256);
  float4 v2 = *reinterpret_cast<const float4*>(p + lane*4 + 512);
  float s  = v0.x+v0.y+v0.z+v0.w + v1.x+v1.y+v1.z+v1.w + v2.x+v2.y+v2.z+v2.w;
  float sq = v0.x*v0.x+v0.y*v0.y+v0.z*v0.z+v0.w*v0.w
           + v1.x*v1.x+v1.y*v1.y+v1.z*v1.z+v1.w*v1.w
           + v2.x*v2.x+v2.y*v2.y+v2.z*v2.z+v2.w*v2.w;
#pragma unroll
  for (int o=32;o>0;o>>=1){ s += __shfl_xor(s,o); sq += __shfl_xor(sq,o); }
  const float mu = s * (1.f/C_);
  const float rs = rsqrtf(sq*(1.f/C_) - mu*mu + 1e-5f);
  float4 g0 = *reinterpret_cast<const float4*>(gam + lane*4);
  float4 g1 = *reinterpret_cast<const float4*>(gam + lane*4 + 256);
  float4 g2 = *reinterpret_cast<const float4*>(gam + lane*4 + 512);
  float4 b0 = *reinterpret_cast<const float4*>(bet + lane*4);
  float4 b1 = *reinterpret_cast<const float4*>(bet + lane*4 + 256);
  float4 b2 = *reinterpret_cast<const float4*>(bet + lane*4 + 512);
  u16x4 o0, o1, o2;
  o0[0]=f2bf((v0.x-mu)*rs*g0.x+b0.x); o0[1]=f2bf((v0.y-mu)*rs*g0.y+b0.y);
  o0[2]=f2bf((v0.z-mu)*rs*g0.z+b0.z); o0[3]=f2bf((v0.w-mu)*rs*g0.w+b0.w);
  o1[0]=f2bf((v1.x-mu)*rs*g1.x+b1.x); o1[1]=f2bf((v1.y-mu)*rs*g1.y+b1.y);
  o1[2]=f2bf((v1.z-mu)*rs*g1.z+b1.z); o1[3]=f2bf((v1.w-mu)*rs*g1.w+b1.w);
  o2[0]=f2bf((v2.x-mu)*rs*g2.x+b2.x); o2[1]=f2bf((v2.y-mu)*rs*g2.y+b2.y);
  o2[2]=f2bf((v2.z-mu)*rs*g2.z+b2.z); o2[3]=f2bf((v2.w-mu)*rs*g2.w+b2.w);
  *reinterpret_cast<u16x4*>(op + lane*4)       = o0;
  *reinterpret_cast<u16x4*>(op + lane*4 + 256) = o1;
  *reinterpret_cast<u16x4*>(op + lane*4 + 512) = o2;
}

__global__ __launch_bounds__(256) void ln_fwd(const float* __restrict__ in,
    const float* __restrict__ gam, const float* __restrict__ bet,
    u16* __restrict__ out)
{
  const int row  = blockIdx.x*4 + (threadIdx.x >> 6);
  const int lane = threadIdx.x & 63;
  ln_row(in + (size_t)row*C_, gam, bet, out + (size_t)row*C_, lane);
}

__global__ __launch_bounds__(256) void ln_fwd2(const float* __restrict__ inx,
    const float* __restrict__ iny, const float* __restrict__ gam,
    const float* __restrict__ bet, u16* __restrict__ outx, u16* __restrict__ outy)
{
  const int row  = blockIdx.x*4 + (threadIdx.x >> 6);
  const int lane = threadIdx.x & 63;
  const float* in = blockIdx.y ? iny : inx;
  u16* out = blockIdx.y ? outy : outx;
  ln_row(in + (size_t)row*C_, gam, bet, out + (size_t)row*C_, lane);
}

// ---------------- f32 -> bf16 convert, x and y in one launch ----------------
__global__ __launch_bounds__(256) void cvt2_bf16(const float* __restrict__ inx,
    const float* __restrict__ iny, u16* __restrict__ outx, u16* __restrict__ outy,
    int n4)
{
  int i = blockIdx.x*256 + threadIdx.x;
  const float* in = blockIdx.y ? iny : inx;
  u16* out = blockIdx.y ? outy : outx;
  if (i < n4){
    float4 v = reinterpret_cast<const float4*>(in)[i];
    u16x4 o; o[0]=f2bf(v.x); o[1]=f2bf(v.y); o[2]=f2bf(v.z); o[3]=f2bf(v.w);
    *reinterpret_cast<u16x4*>(out + (size_t)i*4) = o;
  }
}

// ---------------- all 7 weight transposes in one launch ----------------
__device__ __forceinline__ void tr_tile(const float* __restrict__ in,
    u16* __restrict__ outp, int R, int Cc, int t)
{
  __shared__ float tile[32][33];
  const int tilesx = Cc >> 5;
  const int c0 = (t % tilesx)*32, r0 = (t / tilesx)*32;
  const int tx = threadIdx.x & 31, ty = threadIdx.x >> 5;
#pragma unroll
  for (int i=0;i<32;i+=8)
    tile[ty+i][tx] = in[(size_t)(r0+ty+i)*Cc + c0+tx];
  __syncthreads();
#pragma unroll
  for (int i=0;i<32;i+=8)
    outp[(size_t)(c0+ty+i)*R + r0+tx] = f2bf(tile[tx][ty+i]);
}

__global__ __launch_bounds__(256) void transpose_all(
    const float* Wk, const float* Wpx, const float* Wpy,
    const float* f1x, const float* f2x, const float* f1y, const float* f2y,
    u16* WkT, u16* WpxT, u16* WpyT, u16* f1xT, u16* f2xT, u16* f1yT, u16* f2yT)
{
  int t = blockIdx.x;
  if (t < 1728){
    const int m = t / 576; t -= m*576;
    const float* in = (m==0)?Wk:((m==1)?Wpx:Wpy);
    u16* o = (m==0)?WkT:((m==1)?WpxT:WpyT);
    tr_tile(in, o, C_, C_, t);
  } else {
    t -= 1728;
    const int m = t / 2304; t -= m*2304;
    if (m==0)      tr_tile(f1x, f1xT, C_, H_, t);
    else if (m==1) tr_tile(f2x, f2xT, H_, C_, t);
    else if (m==2) tr_tile(f1y, f1yT, C_, H_, t);
    else           tr_tile(f2y, f2yT, H_, C_, t);
  }
}

// ---------------- masked pooling partials of yn (+ mask partial) ----------------
__global__ __launch_bounds__(256) void pool_partial(const u16* __restrict__ q,
    const float* __restrict__ mask, float* __restrict__ pm, float* __restrict__ pa,
    float* __restrict__ mpart)
{
  const int c = blockIdx.x*256 + threadIdx.x;
  const int b = blockIdx.y, z = blockIdx.z;
  const int n0 = z*(N_/NSPLIT);
  const u16* qp = q + ((size_t)b*N_ + n0)*C_ + c;
  const float* mp = mask + (size_t)b*N_ + n0;
  float am=0.f, aa=0.f, ms=0.f;
  for (int n=0;n<N_/NSPLIT;n++){
    float v = bf2f(qp[(size_t)n*C_]);
    float m = mp[n];
    am += v*m; aa += v; ms += m;
  }
  const size_t o = ((size_t)z*B_ + b)*C_ + c;
  pm[o]=am; pa[o]=aa;
  if (blockIdx.x==0 && threadIdx.x==0) mpart[z*B_+b] = ms;
}

// ---------------- proto_fused: pool_final + (fg,bg)=pooled@Wq + norms ----------------
__global__ __launch_bounds__(256) void proto_fused(const float* __restrict__ pm,
    const float* __restrict__ pa, const float* __restrict__ mpart,
    const float* __restrict__ Wq,
    float* __restrict__ fg, float* __restrict__ bg,
    float* __restrict__ fgn, float* __restrict__ bgn)
{
  __shared__ float fin[C_], bin[C_];
  __shared__ float red[8];
  const int b = blockIdx.x, tid = threadIdx.x;
  float msum_b = 0.f;
#pragma unroll
  for (int z=0;z<NSPLIT;z++) msum_b += mpart[z*B_+b];
  for (int c=tid;c<C_;c+=256){
    float sm=0.f, sa=0.f;
#pragma unroll
    for (int z=0;z<NSPLIT;z++){ size_t o=((size_t)z*B_+b)*C_+c; sm+=pm[o]; sa+=pa[o]; }
    fin[c] = sm/(msum_b + 5e-4f);
    bin[c] = (sa - sm)/((float)N_ - msum_b + 5e-4f);
  }
  __syncthreads();
  const int j0 = tid, j1 = tid+256, j2 = tid+512;
  float f0=0,f1=0,f2=0,g0=0,g1=0,g2=0;
  for (int c=0;c<C_;c++){
    const float* w = Wq + (size_t)c*C_;
    float fc = fin[c], bc = bin[c];
    float w0=w[j0], w1=w[j1], w2=w[j2];
    f0 += fc*w0; f1 += fc*w1; f2 += fc*w2;
    g0 += bc*w0; g1 += bc*w1; g2 += bc*w2;
  }
  fg[b*C_+j0]=f0; fg[b*C_+j1]=f1; fg[b*C_+j2]=f2;
  bg[b*C_+j0]=g0; bg[b*C_+j1]=g1; bg[b*C_+j2]=g2;
  float sf = f0*f0+f1*f1+f2*f2, sb = g0*g0+g1*g1+g2*g2;
#pragma unroll
  for (int o=32;o>0;o>>=1){ sf+=__shfl_down(sf,o); sb+=__shfl_down(sb,o); }
  if ((tid&63)==0){ red[tid>>6]=sf; red[4+(tid>>6)]=sb; }
  __syncthreads();
  if (tid==0){
    fgn[b]=sqrtf(red[0]+red[1]+red[2]+red[3]);
    bgn[b]=sqrtf(red[4]+red[5]+red[6]+red[7]);
  }
}

// ---------------- cosine scores: wave-per-token ----------------
__global__ __launch_bounds__(256) void score_kernel(const u16* __restrict__ k,
    const float* __restrict__ fg, const float* __restrict__ bg,
    const float* __restrict__ fgn, const float* __restrict__ bgn,
    float* __restrict__ fg_s, float* __restrict__ bg_s)
{
  const int t = blockIdx.x*4 + (threadIdx.x >> 6);
  const int lane = threadIdx.x & 63;
  const int b = t >> 12;
  const u16* kp = k + (size_t)t*C_;
  u16x8 k8 = *reinterpret_cast<const u16x8*>(kp + lane*8);
  u16x4 k4 = *reinterpret_cast<const u16x4*>(kp + 512 + lane*4);
  const float* fgp = fg + b*C_;
  const float* bgp = bg + b*C_;
  float4 fa = *reinterpret_cast<const float4*>(fgp + lane*8);
  float4 fb = *reinterpret_cast<const float4*>(fgp + lane*8 + 4);
  float4 fc = *reinterpret_cast<const float4*>(fgp + 512 + lane*4);
  float4 ba = *reinterpret_cast<const float4*>(bgp + lane*8);
  float4 bb = *reinterpret_cast<const float4*>(bgp + lane*8 + 4);
  float4 bc = *reinterpret_cast<const float4*>(bgp + 512 + lane*4);
  float kv[12];
#pragma unroll
  for (int i=0;i<8;i++) kv[i] = bf2f(k8[i]);
#pragma unroll
  for (int i=0;i<4;i++) kv[8+i] = bf2f(k4[i]);
  float df = kv[0]*fa.x+kv[1]*fa.y+kv[2]*fa.z+kv[3]*fa.w
           + kv[4]*fb.x+kv[5]*fb.y+kv[6]*fb.z+kv[7]*fb.w
           + kv[8]*fc.x+kv[9]*fc.y+kv[10]*fc.z+kv[11]*fc.w;
  float db = kv[0]*ba.x+kv[1]*ba.y+kv[2]*ba.z+kv[3]*ba.w
           + kv[4]*bb.x+kv[5]*bb.y+kv[6]*bb.z+kv[7]*bb.w
           + kv[8]*bc.x+kv[9]*bc.y+kv[10]*bc.z+kv[11]*bc.w;
  float kk=0.f;
#pragma unroll
  for (int i=0;i<12;i++) kk += kv[i]*kv[i];
#pragma unroll
  for (int o=32;o>0;o>>=1){
    df+=__shfl_xor(df,o); db+=__shfl_xor(db,o); kk+=__shfl_xor(kk,o);
  }
  if (lane==0){
    const float kn = sqrtf(kk);
    fg_s[t] = df/(kn*fgn[b]+1e-7f);
    bg_s[t] = db/(kn*bgn[b]+1e-7f);
  }
}

__global__ __launch_bounds__(256) void minmax_kernel(const float* __restrict__ fg_s,
    const float* __restrict__ bg_s, float* __restrict__ mm)
{
  __shared__ float sm[16];
  const int b = blockIdx.x;
  float mnf=1e30f, mxf=-1e30f, mnb=1e30f, mxb=-1e30f;
  for (int i=threadIdx.x;i<N_;i+=256){
    float a = fg_s[(size_t)b*N_+i]; mnf=fminf(mnf,a); mxf=fmaxf(mxf,a);
    float c = bg_s[(size_t)b*N_+i]; mnb=fminf(mnb,c); mxb=fmaxf(mxb,c);
  }
#pragma unroll
  for (int o=32;o>0;o>>=1){
    mnf=fminf(mnf,__shfl_down(mnf,o)); mxf=fmaxf(mxf,__shfl_down(mxf,o));
    mnb=fminf(mnb,__shfl_down(mnb,o)); mxb=fmaxf(mxb,__shfl_down(mxb,o));
  }
  const int wid = threadIdx.x>>6;
  if ((threadIdx.x&63)==0){ sm[wid]=mnf; sm[4+wid]=mxf; sm[8+wid]=mnb; sm[12+wid]=mxb; }
  __syncthreads();
  if (threadIdx.x==0){
    mm[b*4+0]=fminf(fminf(sm[0],sm[1]),fminf(sm[2],sm[3]));
    mm[b*4+1]=fmaxf(fmaxf(sm[4],sm[5]),fmaxf(sm[6],sm[7]));
    mm[b*4+2]=fminf(fminf(sm[8],sm[9]),fminf(sm[10],sm[11]));
    mm[b*4+3]=fmaxf(fmaxf(sm[12],sm[13]),fmaxf(sm[14],sm[15]));
  }
}

// scores -> pseudo out + exp weights + denom, one block per b (1024 thr)
__global__ __launch_bounds__(1024) void scorefin_fused(const float* __restrict__ fg_s,
    const float* __restrict__ bg_s, const float* __restrict__ mm,
    float* __restrict__ pseudo, float* __restrict__ escr, float* __restrict__ denom)
{
  __shared__ float sm[16];
  const int b = blockIdx.x, tid = threadIdx.x;
  const float mnf=mm[b*4+0], mxf=mm[b*4+1], mnb=mm[b*4+2], mxb=mm[b*4+3];
  const float rf = 1.f/(mxf-mnf+1e-7f), rb = 1.f/(mxb-mnb+1e-7f);
  float ps = 0.f;
#pragma unroll
  for (int i=0;i<4;i++){
    const int t = tid + i*1024;
    const size_t o = (size_t)b*N_ + t;
    const float s = (fg_s[o]-mnf)*rf - (bg_s[o]-mnb)*rb;
    pseudo[o] = s;
    const float e = expf(s < 0.f ? s - 100.f : s);
    escr[o] = e;
    ps += e;
  }
#pragma unroll
  for (int o=32;o>0;o>>=1) ps += __shfl_down(ps,o);
  if ((tid&63)==0) sm[tid>>6]=ps;
  __syncthreads();
  if (tid==0){
    float s=0.f;
#pragma unroll
    for (int w=0;w<16;w++) s+=sm[w];
    denom[b]=s;
  }
}

// attn-pool partials of xn
__global__ __launch_bounds__(256) void vpool_partial(const u16* __restrict__ xn,
    const float* __restrict__ e, float* __restrict__ pv)
{
  const int c = blockIdx.x*256 + threadIdx.x;
  const int b = blockIdx.y, z = blockIdx.z;
  const int n0 = z*(N_/NSPLIT);
  const u16* vp = xn + ((size_t)b*N_ + n0)*C_ + c;
  const float* ep = e + (size_t)b*N_ + n0;
  float acc=0.f;
  for (int n=0;n<N_/NSPLIT;n++) acc += bf2f(vp[(size_t)n*C_])*ep[n];
  pv[((size_t)z*B_+b)*C_+c] = acc;
}

// pro_fused: vpool_final + qp=vin@Wv + sim + pro + rowx/rowy = pro@Wp*B
__global__ __launch_bounds__(256) void pro_fused(const float* __restrict__ pv,
    const float* __restrict__ denom,
    const float* __restrict__ Wv, const float* __restrict__ Wpx,
    const float* __restrict__ Wpy,
    const float* __restrict__ fg, const float* __restrict__ fgn,
    float* __restrict__ rowx, float* __restrict__ rowy)
{
  __shared__ float vin[C_];
  __shared__ float red[8];
  __shared__ float simsh;
  const int b = blockIdx.x, tid = threadIdx.x;
  const float den = 1.f/denom[b];
  for (int c=tid;c<C_;c+=256){
    float s=0.f;
#pragma unroll
    for (int z=0;z<NSPLIT;z++) s += pv[((size_t)z*B_+b)*C_+c];
    vin[c] = s*den;
  }
  __syncthreads();
  const int j0 = tid, j1 = tid+256, j2 = tid+512;
  float q0=0,q1=0,q2=0;
  for (int c=0;c<C_;c++){
    const float* w = Wv + (size_t)c*C_;
    float vv = vin[c];
    q0 += vv*w[j0]; q1 += vv*w[j1]; q2 += vv*w[j2];
  }
  const float fg0 = fg[b*C_+j0], fg1 = fg[b*C_+j1], fg2 = fg[b*C_+j2];
  float d = q0*fg0 + q1*fg1 + q2*fg2;
  float qq = q0*q0 + q1*q1 + q2*q2;
#pragma unroll
  for (int o=32;o>0;o>>=1){ d+=__shfl_down(d,o); qq+=__shfl_down(qq,o); }
  if ((tid&63)==0){ red[tid>>6]=d; red[4+(tid>>6)]=qq; }
  __syncthreads();
  if (tid==0){
    float dd=red[0]+red[1]+red[2]+red[3], qs=red[4]+red[5]+red[6]+red[7];
    simsh = (dd/(sqrtf(qs)*fgn[b]+1e-7f)+1.f)*0.5f;
  }
  __syncthreads();
  const float sim = simsh;
  vin[j0] = sim*fg0 + (1.f-sim)*q0;
  vin[j1] = sim*fg1 + (1.f-sim)*q1;
  vin[j2] = sim*fg2 + (1.f-sim)*q2;
  __syncthreads();
  float rx0=0,rx1=0,rx2=0, ry0=0,ry1=0,ry2=0;
  for (int c=0;c<C_;c++){
    const float* wx = Wpx + (size_t)(C_+c)*C_;
    const float* wy = Wpy + (size_t)(C_+c)*C_;
    float pc = vin[c];
    rx0 += pc*wx[j0]; rx1 += pc*wx[j1]; rx2 += pc*wx[j2];
    ry0 += pc*wy[j0]; ry1 += pc*wy[j1]; ry2 += pc*wy[j2];
  }
  rowx[b*C_+j0]=rx0; rowx[b*C_+j1]=rx1; rowx[b*C_+j2]=rx2;
  rowy[b*C_+j0]=ry0; rowy[b*C_+j1]=ry1; rowy[b*C_+j2]=ry2;
}

// ---------------- launcher ----------------
extern "C" void kernel_launch(void* const* d_in, const int* in_sizes, int n_in,
                              void* d_out, int out_size, void* d_ws, size_t ws_size,
                              hipStream_t stream)
{
  const float* x     = (const float*)d_in[0];
  const float* y     = (const float*)d_in[1];
  const float* mask  = (const float*)d_in[2];
  const float* ln1_g = (const float*)d_in[5];
  const float* ln1_b = (const float*)d_in[6];
  const float* Wq    = (const float*)d_in[7];
  const float* Wk    = (const float*)d_in[8];
  const float* Wv    = (const float*)d_in[9];
  const float* Wpx   = (const float*)d_in[10];
  const float* Wpy   = (const float*)d_in[11];
  const float* ln2_g = (const float*)d_in[12];
  const float* ln2_b = (const float*)d_in[13];
  const float* fx1_w = (const float*)d_in[14];
  const float* fx1_b = (const float*)d_in[15];
  const float* fx2_w = (const float*)d_in[16];
  const float* fx2_b = (const float*)d_in[17];
  const float* fy1_w = (const float*)d_in[18];
  const float* fy1_b = (const float*)d_in[19];
  const float* fy2_w = (const float*)d_in[20];
  const float* fy2_b = (const float*)d_in[21];

  float* out    = (float*)d_out;
  float* out_xo = out;
  float* out_yo = out + (size_t)M_*C_;
  float* out_ps = out + 2*(size_t)M_*C_;

  char* ws = (char*)d_ws;
  const size_t ACT = (size_t)M_*C_;
  u16* R0  = (u16*)ws;
  u16* xnb = R0;                           // slot0: xn (later: x bf16)
  u16* ynb = R0 + ACT;                     // slot1: yn (later: y bf16)
  u16* kb  = R0 + 2*ACT;                   // slot2: k
  u16* hid = R0;                           // MLP hidden aliases slots 0-3
  u16* qb  = (u16*)(ws + 4*ACT*2);         // slot4: ln2 out
  u16* wp  = (u16*)(ws + 5*ACT*2);
  u16* WkT  = wp;
  u16* WpxT = wp + 1*589824;
  u16* WpyT = wp + 2*589824;
  u16* fx1T = wp + 3*589824;
  u16* fx2T = fx1T + 2359296;
  u16* fy1T = fx2T + 2359296;
  u16* fy2T = fy1T + 2359296;
  float* st   = (float*)(ws + 5*ACT*2 + (size_t)(3*589824 + 4*2359296)*2);
  float* fgn  = st + 8;
  float* bgn  = st + 16;
  float* denom= st + 24;
  float* mm   = st + 32;
  float* fg   = st + 64;
  float* bg   = st + 6208;
  float* rowx = st + 24640;
  float* rowy = st + 30784;
  float* fg_s = st + 37056;
  float* bg_s = st + 69824;
  float* escr = st + 102592;
  float* pm   = st + 135360;
  float* pa   = st + 233664;
  float* pv   = st + 331968;
  float* mpart= st + 430272;

  dim3 tb(256);
  dim3 tg(512);

  // --- weights -> bf16 [N,K] + LN1(x,y) ---
  transpose_all<<<dim3(10944),tb,0,stream>>>(Wk,Wpx,Wpy,fx1_w,fx2_w,fy1_w,fy2_w,
                                             WkT,WpxT,WpyT,fx1T,fx2T,fy1T,fy2T);
  ln_fwd2<<<dim3(M_/4,2),tb,0,stream>>>(x, y, ln1_g, ln1_b, xnb, ynb);

  // --- k GEMM (q,v eliminated by pooling linearity) ---
  gemm_bf16<0><<<dim3(128*6),tg,0,stream>>>(xnb, WkT, C_, C_, 6, kb, nullptr,nullptr,nullptr);

  // --- prototypes fg,bg (f32 path) ---
  pool_partial<<<dim3(3,B_,NSPLIT),tb,0,stream>>>(ynb, mask, pm, pa, mpart);
  proto_fused<<<B_,tb,0,stream>>>(pm, pa, mpart, Wq, fg, bg, fgn, bgn);

  // --- cosine scores + softmax weights ---
  score_kernel<<<M_/4,tb,0,stream>>>(kb, fg, bg, fgn, bgn, fg_s, bg_s);
  minmax_kernel<<<B_,tb,0,stream>>>(fg_s, bg_s, mm);
  scorefin_fused<<<B_,dim3(1024),0,stream>>>(fg_s, bg_s, mm, out_ps, escr, denom);

  // --- query_pro path + pro + row-vectors ---
  vpool_partial<<<dim3(3,B_,NSPLIT),tb,0,stream>>>(xnb, escr, pv);
  pro_fused<<<B_,tb,0,stream>>>(pv, denom, Wv, Wpx, Wpy, fg, fgn, rowx, rowy);

  // --- x,y -> bf16 (xn/yn dead now) ---
  cvt2_bf16<<<dim3((ACT/4+255)/256,2),tb,0,stream>>>(x, y, xnb, ynb, (int)(ACT/4));

  // --- projection GEMMs: out = resid + act@WpA + pro@WpB ---
  gemm_bf16<1><<<dim3(128*6),tg,0,stream>>>(xnb, WpxT, C_, C_, 6, out_xo, x, rowx, nullptr);
  gemm_bf16<1><<<dim3(128*6),tg,0,stream>>>(ynb, WpyT, C_, C_, 6, out_yo, y, rowy, nullptr);

  // --- x MLP ---
  ln_fwd<<<M_/4,tb,0,stream>>>(out_xo, ln2_g, ln2_b, qb);
  gemm_bf16<2><<<dim3(128*24),tg,0,stream>>>(qb, fx1T, C_, H_, 24, hid, nullptr,nullptr, fx1_b);
  gemm_bf16<3><<<dim3(128*6),tg,0,stream>>>(hid, fx2T, H_, C_, 6, out_xo, nullptr,nullptr, fx2_b);

  // --- y MLP ---
  ln_fwd<<<M_/4,tb,0,stream>>>(out_yo, ln2_g, ln2_b, qb);
  gemm_bf16<2><<<dim3(128*24),tg,0,stream>>>(qb, fy1T, C_, H_, 24, hid, nullptr,nullptr, fy1_b);
  gemm_bf16<3><<<dim3(128*6),tg,0,stream>>>(hid, fy2T, H_, C_, 6, out_yo, nullptr,nullptr, fy2_b);
}